// Round 13
// baseline (12776.619 us; speedup 1.0000x reference)
//
#include <hip/hip_runtime.h>
#include <type_traits>

// ---------------------------------------------------------------------------
// CSAAttention — round 13.
//   Selection path: Q/K/Kc via probed f64-MFMA (R12-validated) with LDS pad
//   68->72 (bank-conflict fix; arithmetic bit-identical). Dots+topk+PV fused
//   into ONE kernel (dotk_k): ascending-d fp64 chains bit-identical to the
//   frozen gemm_k dot values; radix top-64 / softmax / PV per row in-kernel.
//   No fp64 dot planes in ws anymore. Value path (V, Vc, Wo): R9 verbatim.
// ---------------------------------------------------------------------------

#define DEVI __device__ __forceinline__

constexpr int Tn = 1024;
constexpr int Cn = 1024;
constexpr int Hn = 16;

typedef short bf16x8 __attribute__((ext_vector_type(8)));
typedef float f32x4 __attribute__((ext_vector_type(4)));
typedef double f64x4 __attribute__((ext_vector_type(4)));

DEVI int wsumi(int v)   { for (int m = 1; m < 64; m <<= 1) v += __shfl_xor(v, m); return v; }
DEVI int wmini(int v)   { for (int m = 1; m < 64; m <<= 1) { int o = __shfl_xor(v, m); v = o < v ? o : v; } return v; }
DEVI float wfmax(float v){ for (int m = 1; m < 64; m <<= 1) v = fmaxf(v, __shfl_xor(v, m)); return v; }
DEVI float wfsum(float v){ for (int m = 1; m < 64; m <<= 1) v += __shfl_xor(v, m); return v; }

DEVI unsigned long long mapd(double x) {  // monotone fp64 -> uint64
  unsigned long long b = (unsigned long long)__double_as_longlong(x);
  return (b >> 63) ? ~b : (b | 0x8000000000000000ull);
}

DEVI unsigned short f2bf_rne(float x) {
  unsigned u = __float_as_uint(x);
  u += 0x7fffu + ((u >> 16) & 1u);
  return (unsigned short)(u >> 16);
}
struct BfPair { short hi, lo; };
DEVI BfPair split2(float x) {
  unsigned short h = f2bf_rne(x);
  float hf = __uint_as_float(((unsigned)h) << 16);
  BfPair r;
  r.hi = (short)h;
  r.lo = (short)f2bf_rne(x - hf);
  return r;
}

// ---------------------------------------------------------------------------
// Selection-path fp64 GEMM, probed f64-MFMA (R12-validated), LDS stride 72
// (68 -> 72: 4-way bank conflicts -> 2-way free; arithmetic identical).
// C = A * op(B) (+bias). Tile 64x64, 4 waves, BK=16.
// ---------------------------------------------------------------------------
template <bool BTRANS, int BIASMODE>
__global__ __launch_bounds__(256) void f64sel_k(
    const float* __restrict__ A, const float* __restrict__ B,
    const float* __restrict__ bias, float* __restrict__ C,
    int Kd, int lda, int ldb, int ldc, long long zB, long long zC)
{
  __shared__ float As[16][72];
  __shared__ float Bs[16][72];

  const float* Ab = A;
  const float* Bb = B + (size_t)blockIdx.z * (size_t)zB;
  float* Cb = C + (size_t)blockIdx.z * (size_t)zC;

  const int tid = threadIdx.x;
  const int lane = tid & 63, w = tid >> 6;
  const int wr = w >> 1, wc = w & 1;
  const int l15 = lane & 15, l4 = lane >> 4;
  const int m0 = blockIdx.y * 64, n0 = blockIdx.x * 64;

  // runtime layout probe (wave-uniform) — R12-validated
  f64x4 zz = {0.0, 0.0, 0.0, 0.0};
  f64x4 p1 = __builtin_amdgcn_mfma_f64_16x16x4f64(1.0, (double)l15, zz, 0, 0, 0);
  f64x4 p2 = __builtin_amdgcn_mfma_f64_16x16x4f64((double)l15, 1.0, zz, 0, 0, 0);
  int a1 = 1, b1 = 1, c1 = 1, a2 = 1, b2 = 1, c2 = 1;
#pragma unroll
  for (int rr = 0; rr < 4; ++rr) {
    a1 &= (p1[rr] == 4.0 * l15);
    b1 &= (p1[rr] == 4.0 * (l4 * 4 + rr));
    c1 &= (p1[rr] == 4.0 * (l4 + 4 * rr));
    a2 &= (p2[rr] == 4.0 * (l4 * 4 + rr));
    b2 &= (p2[rr] == 4.0 * (l4 + 4 * rr));
    c2 &= (p2[rr] == 4.0 * l15);
  }
  a1 = __all(a1); b1 = __all(b1); c1 = __all(c1);
  a2 = __all(a2); b2 = __all(b2); c2 = __all(c2);
  int dmap = 0, useM = 1;
  if      (a1 && a2) dmap = 0;
  else if (a1 && b2) dmap = 1;
  else if (b1 && c2) dmap = 2;
  else if (c1 && c2) dmap = 3;
  else useM = 0;

  f64x4 acc[2][2];
#pragma unroll
  for (int i = 0; i < 2; ++i)
#pragma unroll
    for (int j = 0; j < 2; ++j) acc[i][j] = (f64x4){0.0, 0.0, 0.0, 0.0};

  for (int k0 = 0; k0 < Kd; k0 += 16) {
    {
      int m = tid >> 2, kf = tid & 3;
      float4 a = *(const float4*)(Ab + (size_t)(m0 + m) * lda + k0 + 4 * kf);
      As[4 * kf + 0][m] = a.x; As[4 * kf + 1][m] = a.y;
      As[4 * kf + 2][m] = a.z; As[4 * kf + 3][m] = a.w;
    }
    if (BTRANS) {
      int n = tid >> 2, kf = tid & 3;
      float4 b = *(const float4*)(Bb + (size_t)(n0 + n) * ldb + k0 + 4 * kf);
      Bs[4 * kf + 0][n] = b.x; Bs[4 * kf + 1][n] = b.y;
      Bs[4 * kf + 2][n] = b.z; Bs[4 * kf + 3][n] = b.w;
    } else {
      int k = tid >> 4, nf = tid & 15;
      float4 b = *(const float4*)(Bb + (size_t)(k0 + k) * ldb + n0 + 4 * nf);
      *(float4*)&Bs[k][4 * nf] = b;
    }
    __syncthreads();

    if (useM) {
#pragma unroll
      for (int kq = 0; kq < 4; ++kq) {
        int kk = kq * 4 + l4;
        double a0  = (double)As[kk][wr * 32 + l15];
        double a1v = (double)As[kk][wr * 32 + 16 + l15];
        double b0  = (double)Bs[kk][wc * 32 + l15];
        double b1v = (double)Bs[kk][wc * 32 + 16 + l15];
        acc[0][0] = __builtin_amdgcn_mfma_f64_16x16x4f64(a0,  b0,  acc[0][0], 0, 0, 0);
        acc[0][1] = __builtin_amdgcn_mfma_f64_16x16x4f64(a0,  b1v, acc[0][1], 0, 0, 0);
        acc[1][0] = __builtin_amdgcn_mfma_f64_16x16x4f64(a1v, b0,  acc[1][0], 0, 0, 0);
        acc[1][1] = __builtin_amdgcn_mfma_f64_16x16x4f64(a1v, b1v, acc[1][1], 0, 0, 0);
      }
    } else {
#pragma unroll
      for (int k = 0; k < 16; ++k) {
        double bv0 = (double)Bs[k][wc * 32 + l15];
        double bv1 = (double)Bs[k][wc * 32 + 16 + l15];
#pragma unroll
        for (int fr = 0; fr < 2; ++fr)
#pragma unroll
          for (int rr = 0; rr < 4; ++rr) {
            double av = (double)As[k][wr * 32 + fr * 16 + l4 * 4 + rr];
            acc[fr][0][rr] += av * bv0;
            acc[fr][1][rr] += av * bv1;
          }
      }
    }
    __syncthreads();
  }

#pragma unroll
  for (int fr = 0; fr < 2; ++fr)
#pragma unroll
    for (int fc = 0; fc < 2; ++fc)
#pragma unroll
      for (int rr = 0; rr < 4; ++rr) {
        int ri, ci;
        if (!useM || dmap == 0) { ri = l4 * 4 + rr; ci = l15; }
        else if (dmap == 1)     { ri = l4 + 4 * rr; ci = l15; }
        else if (dmap == 2)     { ri = l15; ci = l4 * 4 + rr; }
        else                    { ri = l15; ci = l4 + 4 * rr; }
        int row = m0 + wr * 32 + fr * 16 + ri;
        int col = n0 + wc * 32 + fc * 16 + ci;
        float s = (float)acc[fr][fc][rr];
        float cb = (BIASMODE == 1) ? bias[col] : 0.f;
        float rb = (BIASMODE == 2) ? bias[row] : 0.f;
        Cb[(size_t)row * ldc + col] = s + cb + rb;
      }
}

// ---------------------------------------------------------------------------
// Value-path MFMA GEMM, split-in-kernel (R9-validated, unchanged).
// ---------------------------------------------------------------------------
template <bool BTRANS, int BIASMODE>
__global__ __launch_bounds__(256) void mfma_gemm_k(
    const float* __restrict__ A, const float* __restrict__ B,
    const float* __restrict__ bias, float* __restrict__ C,
    int Kd, int lda, int ldb, int ldc, long long zB, long long zC)
{
  __shared__ short Ah[4 * 64 * 8];
  __shared__ short Al[4 * 64 * 8];
  __shared__ short Bh[4 * 64 * 8];
  __shared__ short Bl[4 * 64 * 8];

  const float* Bz = B + (size_t)blockIdx.z * (size_t)zB;
  float* Cz = C + (size_t)blockIdx.z * (size_t)zC;

  const int tid = threadIdx.x;
  const int lane = tid & 63, w = tid >> 6;
  const int wr = w >> 1, wc = w & 1;
  const int m0 = blockIdx.y * 64, n0 = blockIdx.x * 64;
  const int r16 = lane & 15, kg = lane >> 4;

  f32x4 acc[2][2];
#pragma unroll
  for (int i = 0; i < 2; ++i)
#pragma unroll
    for (int j = 0; j < 2; ++j) acc[i][j] = (f32x4){0.f, 0.f, 0.f, 0.f};

  for (int k0 = 0; k0 < Kd; k0 += 32) {
    {
      int row = tid >> 2, kseg = tid & 3;
      const float* p = A + (size_t)(m0 + row) * lda + k0 + kseg * 8;
      float4 v0 = *(const float4*)p;
      float4 v1 = *(const float4*)(p + 4);
      BfPair q0 = split2(v0.x), q1 = split2(v0.y), q2 = split2(v0.z), q3 = split2(v0.w);
      BfPair q4 = split2(v1.x), q5 = split2(v1.y), q6 = split2(v1.z), q7 = split2(v1.w);
      bf16x8 h = {q0.hi, q1.hi, q2.hi, q3.hi, q4.hi, q5.hi, q6.hi, q7.hi};
      bf16x8 l = {q0.lo, q1.lo, q2.lo, q3.lo, q4.lo, q5.lo, q6.lo, q7.lo};
      int idx = (kseg * 64 + row) * 8;
      *(bf16x8*)&Ah[idx] = h;
      *(bf16x8*)&Al[idx] = l;
    }
    if (BTRANS) {
      int row = tid >> 2, kseg = tid & 3;
      const float* p = Bz + (size_t)(n0 + row) * ldb + k0 + kseg * 8;
      float4 v0 = *(const float4*)p;
      float4 v1 = *(const float4*)(p + 4);
      BfPair q0 = split2(v0.x), q1 = split2(v0.y), q2 = split2(v0.z), q3 = split2(v0.w);
      BfPair q4 = split2(v1.x), q5 = split2(v1.y), q6 = split2(v1.z), q7 = split2(v1.w);
      bf16x8 h = {q0.hi, q1.hi, q2.hi, q3.hi, q4.hi, q5.hi, q6.hi, q7.hi};
      bf16x8 l = {q0.lo, q1.lo, q2.lo, q3.lo, q4.lo, q5.lo, q6.lo, q7.lo};
      int idx = (kseg * 64 + row) * 8;
      *(bf16x8*)&Bh[idx] = h;
      *(bf16x8*)&Bl[idx] = l;
    } else {
      int col = tid & 63, kseg = tid >> 6;
      short hv[8], lv[8];
#pragma unroll
      for (int j = 0; j < 8; ++j) {
        BfPair p = split2(Bz[(size_t)(k0 + kseg * 8 + j) * ldb + n0 + col]);
        hv[j] = p.hi; lv[j] = p.lo;
      }
      bf16x8 h = {hv[0], hv[1], hv[2], hv[3], hv[4], hv[5], hv[6], hv[7]};
      bf16x8 l = {lv[0], lv[1], lv[2], lv[3], lv[4], lv[5], lv[6], lv[7]};
      int idx = (kseg * 64 + col) * 8;
      *(bf16x8*)&Bh[idx] = h;
      *(bf16x8*)&Bl[idx] = l;
    }
    __syncthreads();

    bf16x8 ah[2], al[2], bh[2], bl[2];
#pragma unroll
    for (int f = 0; f < 2; ++f) {
      int ia = (kg * 64 + wr * 32 + f * 16 + r16) * 8;
      int ib = (kg * 64 + wc * 32 + f * 16 + r16) * 8;
      ah[f] = *(const bf16x8*)&Ah[ia];
      al[f] = *(const bf16x8*)&Al[ia];
      bh[f] = *(const bf16x8*)&Bh[ib];
      bl[f] = *(const bf16x8*)&Bl[ib];
    }
#pragma unroll
    for (int fr = 0; fr < 2; ++fr)
#pragma unroll
      for (int fc = 0; fc < 2; ++fc) {
        f32x4 c = acc[fr][fc];
        c = __builtin_amdgcn_mfma_f32_16x16x32_bf16(al[fr], bh[fc], c, 0, 0, 0);
        c = __builtin_amdgcn_mfma_f32_16x16x32_bf16(ah[fr], bl[fc], c, 0, 0, 0);
        c = __builtin_amdgcn_mfma_f32_16x16x32_bf16(ah[fr], bh[fc], c, 0, 0, 0);
        acc[fr][fc] = c;
      }
    __syncthreads();
  }

#pragma unroll
  for (int fr = 0; fr < 2; ++fr)
#pragma unroll
    for (int fc = 0; fc < 2; ++fc) {
      int col = n0 + wc * 32 + fc * 16 + r16;
      float cb = (BIASMODE == 1) ? bias[col] : 0.f;
#pragma unroll
      for (int rr = 0; rr < 4; ++rr) {
        int rw = m0 + wr * 32 + fr * 16 + kg * 4 + rr;
        float rb = (BIASMODE == 2) ? bias[rw] : 0.f;
        Cz[(size_t)rw * ldc + col] = acc[fr][fc][rr] + cb + rb;
      }
    }
}

// kn[b*16+h][c] = 1 / max(||Kc[b, c, h*64 : +64]||, 1e-12)   (fp64)
__global__ __launch_bounds__(256) void kn_k2(const float* __restrict__ Kc,
                                             double* __restrict__ kn)
{
  int idx = (int)blockIdx.x * 256 + (int)threadIdx.x;
  int c = idx & 1023;
  int p = idx >> 10;
  int b = p >> 4, h = p & 15;
  const float* row = Kc + ((size_t)(b * 1024 + c)) * 1024 + h * 64;
  double s = 0.0;
  for (int d = 0; d < 64; ++d) { double v = (double)row[d]; s += v * v; }
  kn[(size_t)p * 1024 + c] = 1.0 / fmax(sqrt(s), 1e-12);
}

// ---------------------------------------------------------------------------
// Fused dots + exact top-64 + softmax + PV.  One block = 8 t-rows of one
// (b,h) pair (4 waves x 2 rows).  Dots: ascending-d fp64 FMA chains on fp32
// Q/Kc values — BIT-IDENTICAL to the frozen gemm_k dot values.  Then the
// R5-validated radix top-64 (ties -> lowest c) + softmax(dot/8) + PV.
// dv layout: dv[rr][i], c(i,lane) = 128*(i>>1) + 64*(i&1) + lane.
// ---------------------------------------------------------------------------
__global__ __launch_bounds__(256) void dotk_k(
    const double* __restrict__ kn, const float* __restrict__ Q,
    const float* __restrict__ Kc, const float* __restrict__ Vc,
    float* __restrict__ at)
{
  __shared__ float KcS[128][65];   // stride 65 -> (lane + d) % 32 banks, 2-way
  __shared__ float Qs[8][64];
  __shared__ int sC[4][64];
  __shared__ float sD[4][64];

  const int tid = threadIdx.x, lane = tid & 63, wv = tid >> 6;
  const int pair = (int)blockIdx.x >> 7;         // 32 pairs x 128 blocks
  const int r0 = ((int)blockIdx.x & 127) * 8;    // 8 rows per block
  const int bb = pair >> 4, hh = pair & 15;

  const float* Qb = Q + ((size_t)bb * Tn) * 1024 + (size_t)hh * 64;
  const float* Kb = Kc + ((size_t)bb * Cn) * 1024 + (size_t)hh * 64;
  const double* knr = kn + (size_t)pair * Cn;

  // stage this block's 8 Q rows (each thread: 2 floats; wave stages own rows)
  {
    int r = tid >> 5, d = (tid & 31) * 2;
    float2 q = *(const float2*)(Qb + (size_t)(r0 + r) * 1024 + d);
    Qs[r][d] = q.x; Qs[r][d + 1] = q.y;
  }

  double dv[2][16];
#pragma unroll
  for (int ct = 0; ct < 8; ++ct) {
    __syncthreads();  // prev-tile reads done (and Qs visible on first iter)
    {   // stage Kc c-tile [128][64] (scalar writes: stride-65 rows)
      int r = tid >> 1, c0 = (tid & 1) * 32;
      const float* src = Kb + (size_t)(ct * 128 + r) * 1024 + c0;
#pragma unroll
      for (int j = 0; j < 32; ++j) KcS[r][c0 + j] = src[j];
    }
    __syncthreads();

    double a00 = 0.0, a01 = 0.0, a10 = 0.0, a11 = 0.0;
    const int q0r = wv * 2, q1r = wv * 2 + 1;
#pragma unroll
    for (int d = 0; d < 64; ++d) {
      double k0 = (double)KcS[lane][d];
      double k1 = (double)KcS[64 + lane][d];
      double q0 = (double)Qs[q0r][d];
      double q1 = (double)Qs[q1r][d];
      a00 += q0 * k0; a01 += q0 * k1;
      a10 += q1 * k0; a11 += q1 * k1;
    }
    dv[0][2 * ct] = a00; dv[0][2 * ct + 1] = a01;
    dv[1][2 * ct] = a10; dv[1][2 * ct + 1] = a11;
  }

  // per-row: radix top-64 + softmax + PV (R5-validated algorithm)
#pragma unroll
  for (int rr = 0; rr < 2; ++rr) {
    const int t = r0 + wv * 2 + rr;

    unsigned long long u[16];
#pragma unroll
    for (int i = 0; i < 16; ++i) {
      int c = 128 * (i >> 1) + 64 * (i & 1) + lane;
      u[i] = mapd(dv[rr][i] * knr[c]);
    }
    unsigned hi[16];
#pragma unroll
    for (int i = 0; i < 16; ++i) hi[i] = (unsigned)(u[i] >> 32);

    unsigned TH = 0;
    for (int bit = 31; bit >= 0; --bit) {
      unsigned Tc = TH | (1u << bit);
      int c = 0;
#pragma unroll
      for (int i = 0; i < 16; ++i) c += (hi[i] >= Tc);
      if (wsumi(c) >= 64) TH = Tc;
    }
    int mhi = 0;
#pragma unroll
    for (int i = 0; i < 16; ++i) mhi += (hi[i] > TH);
    mhi = wsumi(mhi);
    const int need1 = 64 - mhi;
    unsigned TL = 0;
    for (int bit = 31; bit >= 0; --bit) {
      unsigned Tc = TL | (1u << bit);
      int c = 0;
#pragma unroll
      for (int i = 0; i < 16; ++i) c += (hi[i] == TH && (unsigned)u[i] >= Tc);
      if (wsumi(c) >= need1) TL = Tc;
    }
    const unsigned long long V64 = ((unsigned long long)TH << 32) | TL;

    int base = 0;
#pragma unroll
    for (int i = 0; i < 16; ++i) {
      const int cix = 128 * (i >> 1) + 64 * (i & 1) + lane;
      bool sel = (u[i] > V64);
      unsigned long long mk = __ballot(sel);
      if (sel) {
        int r = __popcll(mk & ((1ull << lane) - 1ull));
        sC[wv][base + r] = cix;
        sD[wv][base + r] = (float)dv[rr][i];
      }
      base += __popcll(mk);
    }
    const int need = 64 - base;
    unsigned taken = 0;
    for (int r = 0; r < need; ++r) {
      int mn = 0x7fffffff;
#pragma unroll
      for (int i = 0; i < 16; ++i) {
        int cix = 128 * (i >> 1) + 64 * (i & 1) + lane;
        if (u[i] == V64 && !((taken >> i) & 1u)) mn = mn < cix ? mn : cix;
      }
      mn = wmini(mn);
#pragma unroll
      for (int i = 0; i < 16; ++i) {
        int cix = 128 * (i >> 1) + 64 * (i & 1) + lane;
        if (u[i] == V64 && !((taken >> i) & 1u) && cix == mn) {
          taken |= 1u << i;
          sC[wv][base + r] = mn;
          sD[wv][base + r] = (float)dv[rr][i];
        }
      }
    }

    // softmax over dot/8, then PV (per-wave LDS region; in-order within wave)
    int ck = sC[wv][lane];
    float sc = sD[wv][lane] * 0.125f;
    float mx = wfmax(sc);
    float w = expf(sc - mx);
    float sw = wfsum(w);
    w /= sw;

    const float* Vb = Vc + (size_t)bb * ((size_t)Cn * 1024) + hh * 64 + lane;
    float acc = 0.f;
#pragma unroll 4
    for (int k = 0; k < 64; ++k) {
      int c = __shfl(ck, k);
      float wk = __shfl(w, k);
      acc = fmaf(wk, Vb[(size_t)c * 1024], acc);
    }
    at[((size_t)(bb * Tn + t)) * 1024 + hh * 64 + lane] = acc;
  }
}

// ---------------------------------------------------------------------------
extern "C" void kernel_launch(void* const* d_in, const int* in_sizes, int n_in,
                              void* d_out, int out_size, void* d_ws, size_t ws_size,
                              hipStream_t stream)
{
  const float* x  = (const float*)d_in[0];
  const float* Wq = (const float*)d_in[1];
  const float* bq = (const float*)d_in[2];
  const float* Wk = (const float*)d_in[3];
  const float* bk = (const float*)d_in[4];
  const float* Wv = (const float*)d_in[5];
  const float* bv = (const float*)d_in[6];
  const float* Wo = (const float*)d_in[7];
  const float* bo = (const float*)d_in[8];
  const float* Wc = (const float*)d_in[9];
  const float* bc = (const float*)d_in[10];
  float* out = (float*)d_out;

  const size_t NE = (size_t)2048 * 1024;
  const size_t M1 = (size_t)1024 * 1024;
  float* Q   = (float*)d_ws;
  float* Kf  = Q + NE;
  float* Vf  = Kf + NE;
  float* Kc  = Vf + NE;
  float* Vc  = Kc + NE;
  float* at  = Vc + NE;
  double* kn = (double*)(at + NE);

  const size_t fixedB = 6 * NE * 4 + 32768 * 8;
  if (ws_size < fixedB) return;

  dim3 blk(256, 1, 1);

  // Selection-path projections (probed f64-MFMA, padded LDS)
  f64sel_k<true, 1><<<dim3(16, 32, 1), blk, 0, stream>>>(
      x, Wq, bq, Q, 1024, 1024, 1024, 1024, 0, 0);
  f64sel_k<true, 1><<<dim3(16, 32, 1), blk, 0, stream>>>(
      x, Wk, bk, Kf, 1024, 1024, 1024, 1024, 0, 0);
  // Value-path V projection (R9-validated)
  mfma_gemm_k<true, 1><<<dim3(16, 32, 1), blk, 0, stream>>>(
      x, Wv, bv, Vf, 1024, 1024, 1024, 1024, 0, 0);

  // Compress: Kc (f64-MFMA), Vc (R9 MFMA), z = batch
  f64sel_k<false, 2><<<dim3(16, 16, 2), blk, 0, stream>>>(
      Wc, Kf, bc, Kc, 1024, 1024, 1024, 1024, (long long)M1, (long long)M1);
  mfma_gemm_k<false, 2><<<dim3(16, 16, 2), blk, 0, stream>>>(
      Wc, Vf, bc, Vc, 1024, 1024, 1024, 1024, (long long)M1, (long long)M1);

  kn_k2<<<dim3(128), blk, 0, stream>>>(Kc, kn);

  // Fused dots + top-64 + softmax + PV (single dispatch, no dot planes)
  dotk_k<<<dim3(4096), blk, 0, stream>>>(kn, Q, Kc, Vc, at);

  // Output projection (R9-validated)
  mfma_gemm_k<true, 1><<<dim3(16, 32, 1), blk, 0, stream>>>(
      at, Wo, bo, out, 1024, 1024, 1024, 1024, 0, 0);
}

// Round 14
// 889.379 us; speedup vs baseline: 14.3658x; 14.3658x over previous
//
#include <hip/hip_runtime.h>
#include <type_traits>

// ---------------------------------------------------------------------------
// CSAAttention — round 14 = round 12 structure (882us best) + ONE change:
//   f64sel_k LDS stride 68 -> 72 (bank-conflict fix; numerics validated in
//   R13 where absmax stayed exactly 0.00390625). Dead tier-A code removed.
//   R13's dotk_k fusion reverted (register-spill catastrophe: 20GB scratch).
// ---------------------------------------------------------------------------

#define DEVI __device__ __forceinline__

constexpr int Tn = 1024;
constexpr int Cn = 1024;
constexpr int Hn = 16;

typedef short bf16x8 __attribute__((ext_vector_type(8)));
typedef float f32x4 __attribute__((ext_vector_type(4)));
typedef double f64x4 __attribute__((ext_vector_type(4)));

DEVI int wsumi(int v)   { for (int m = 1; m < 64; m <<= 1) v += __shfl_xor(v, m); return v; }
DEVI int wmini(int v)   { for (int m = 1; m < 64; m <<= 1) { int o = __shfl_xor(v, m); v = o < v ? o : v; } return v; }
DEVI float wfmax(float v){ for (int m = 1; m < 64; m <<= 1) v = fmaxf(v, __shfl_xor(v, m)); return v; }
DEVI float wfsum(float v){ for (int m = 1; m < 64; m <<= 1) v += __shfl_xor(v, m); return v; }

DEVI unsigned long long mapd(double x) {  // monotone fp64 -> uint64
  unsigned long long b = (unsigned long long)__double_as_longlong(x);
  return (b >> 63) ? ~b : (b | 0x8000000000000000ull);
}

DEVI unsigned short f2bf_rne(float x) {
  unsigned u = __float_as_uint(x);
  u += 0x7fffu + ((u >> 16) & 1u);
  return (unsigned short)(u >> 16);
}
struct BfPair { short hi, lo; };
DEVI BfPair split2(float x) {
  unsigned short h = f2bf_rne(x);
  float hf = __uint_as_float(((unsigned)h) << 16);
  BfPair r;
  r.hi = (short)h;
  r.lo = (short)f2bf_rne(x - hf);
  return r;
}

// ---------------------------------------------------------------------------
// Selection-path fp64 GEMM with probed f64-MFMA (R12-validated), LDS
// stride 72 (R13-validated numerics). Scalar fp64 fallback if probe fails.
// C = A * op(B) (+bias). Tile 64x64, 4 waves (2x2 of 32x32), BK=16.
// SIM: per-z (b,h) slices of Q/Kc -> fp64 dot plane (OUTT=double).
// ---------------------------------------------------------------------------
template <typename OUTT, bool BTRANS, int BIASMODE, bool SIM>
__global__ __launch_bounds__(256) void f64sel_k(
    const float* __restrict__ A, const float* __restrict__ B,
    const float* __restrict__ bias, OUTT* __restrict__ C,
    int Kd, int lda, int ldb, int ldc,
    long long zB, long long zC, int group_base)
{
  __shared__ float As[16][72];
  __shared__ float Bs[16][72];

  size_t offA = 0, offB = 0, offC = 0;
  if (SIM) {
    int pair = group_base + (int)blockIdx.z;
    int bb = pair >> 4, hh = pair & 15;
    offA = ((size_t)bb * Tn) * (size_t)lda + (size_t)hh * 64;
    offB = ((size_t)bb * Cn) * (size_t)ldb + (size_t)hh * 64;
    offC = (size_t)blockIdx.z * (size_t)Tn * (size_t)ldc;
  } else {
    offB = (size_t)blockIdx.z * (size_t)zB;
    offC = (size_t)blockIdx.z * (size_t)zC;
  }
  const float* Ab = A + offA;
  const float* Bb = B + offB;
  OUTT* Cb = C + offC;

  const int tid = threadIdx.x;
  const int lane = tid & 63, w = tid >> 6;
  const int wr = w >> 1, wc = w & 1;
  const int l15 = lane & 15, l4 = lane >> 4;
  const int m0 = blockIdx.y * 64, n0 = blockIdx.x * 64;

  // runtime layout probe (wave-uniform) — R12-validated
  f64x4 zz = {0.0, 0.0, 0.0, 0.0};
  f64x4 p1 = __builtin_amdgcn_mfma_f64_16x16x4f64(1.0, (double)l15, zz, 0, 0, 0);
  f64x4 p2 = __builtin_amdgcn_mfma_f64_16x16x4f64((double)l15, 1.0, zz, 0, 0, 0);
  int a1 = 1, b1 = 1, c1 = 1, a2 = 1, b2 = 1, c2 = 1;
#pragma unroll
  for (int rr = 0; rr < 4; ++rr) {
    a1 &= (p1[rr] == 4.0 * l15);
    b1 &= (p1[rr] == 4.0 * (l4 * 4 + rr));
    c1 &= (p1[rr] == 4.0 * (l4 + 4 * rr));
    a2 &= (p2[rr] == 4.0 * (l4 * 4 + rr));
    b2 &= (p2[rr] == 4.0 * (l4 + 4 * rr));
    c2 &= (p2[rr] == 4.0 * l15);
  }
  a1 = __all(a1); b1 = __all(b1); c1 = __all(c1);
  a2 = __all(a2); b2 = __all(b2); c2 = __all(c2);
  int dmap = 0, useM = 1;
  if      (a1 && a2) dmap = 0;
  else if (a1 && b2) dmap = 1;
  else if (b1 && c2) dmap = 2;
  else if (c1 && c2) dmap = 3;
  else useM = 0;

  f64x4 acc[2][2];
#pragma unroll
  for (int i = 0; i < 2; ++i)
#pragma unroll
    for (int j = 0; j < 2; ++j) acc[i][j] = (f64x4){0.0, 0.0, 0.0, 0.0};

  for (int k0 = 0; k0 < Kd; k0 += 16) {
    {
      int m = tid >> 2, kf = tid & 3;
      float4 a = *(const float4*)(Ab + (size_t)(m0 + m) * lda + k0 + 4 * kf);
      As[4 * kf + 0][m] = a.x; As[4 * kf + 1][m] = a.y;
      As[4 * kf + 2][m] = a.z; As[4 * kf + 3][m] = a.w;
    }
    if (BTRANS) {
      int n = tid >> 2, kf = tid & 3;
      float4 b = *(const float4*)(Bb + (size_t)(n0 + n) * ldb + k0 + 4 * kf);
      Bs[4 * kf + 0][n] = b.x; Bs[4 * kf + 1][n] = b.y;
      Bs[4 * kf + 2][n] = b.z; Bs[4 * kf + 3][n] = b.w;
    } else {
      int k = tid >> 4, nf = tid & 15;
      float4 b = *(const float4*)(Bb + (size_t)(k0 + k) * ldb + n0 + 4 * nf);
      *(float4*)&Bs[k][4 * nf] = b;
    }
    __syncthreads();

    if (useM) {
#pragma unroll
      for (int kq = 0; kq < 4; ++kq) {
        int kk = kq * 4 + l4;
        double a0  = (double)As[kk][wr * 32 + l15];
        double a1v = (double)As[kk][wr * 32 + 16 + l15];
        double b0  = (double)Bs[kk][wc * 32 + l15];
        double b1v = (double)Bs[kk][wc * 32 + 16 + l15];
        acc[0][0] = __builtin_amdgcn_mfma_f64_16x16x4f64(a0,  b0,  acc[0][0], 0, 0, 0);
        acc[0][1] = __builtin_amdgcn_mfma_f64_16x16x4f64(a0,  b1v, acc[0][1], 0, 0, 0);
        acc[1][0] = __builtin_amdgcn_mfma_f64_16x16x4f64(a1v, b0,  acc[1][0], 0, 0, 0);
        acc[1][1] = __builtin_amdgcn_mfma_f64_16x16x4f64(a1v, b1v, acc[1][1], 0, 0, 0);
      }
    } else {
#pragma unroll
      for (int k = 0; k < 16; ++k) {
        double bv0 = (double)Bs[k][wc * 32 + l15];
        double bv1 = (double)Bs[k][wc * 32 + 16 + l15];
#pragma unroll
        for (int fr = 0; fr < 2; ++fr)
#pragma unroll
          for (int rr = 0; rr < 4; ++rr) {
            double av = (double)As[k][wr * 32 + fr * 16 + l4 * 4 + rr];
            acc[fr][0][rr] += av * bv0;
            acc[fr][1][rr] += av * bv1;
          }
      }
    }
    __syncthreads();
  }

  // epilogue (frozen formula: fp64->fp32 cast, then fp32 bias adds)
#pragma unroll
  for (int fr = 0; fr < 2; ++fr)
#pragma unroll
    for (int fc = 0; fc < 2; ++fc)
#pragma unroll
      for (int rr = 0; rr < 4; ++rr) {
        int ri, ci;
        if (!useM || dmap == 0) { ri = l4 * 4 + rr; ci = l15; }
        else if (dmap == 1)     { ri = l4 + 4 * rr; ci = l15; }
        else if (dmap == 2)     { ri = l15; ci = l4 * 4 + rr; }
        else                    { ri = l15; ci = l4 + 4 * rr; }
        int row = m0 + wr * 32 + fr * 16 + ri;
        int col = n0 + wc * 32 + fc * 16 + ci;
        double v = acc[fr][fc][rr];
        if constexpr (std::is_same<OUTT, double>::value) {
          Cb[(size_t)row * ldc + col] = v;
        } else {
          float s = (float)v;
          float cb = (BIASMODE == 1) ? bias[col] : 0.f;
          float rb = (BIASMODE == 2) ? bias[row] : 0.f;
          ((float*)Cb)[(size_t)row * ldc + col] = s + cb + rb;
        }
      }
}

// ---------------------------------------------------------------------------
// Value-path MFMA GEMM, split-in-kernel (R9-validated, unchanged).
// ---------------------------------------------------------------------------
template <bool BTRANS, int BIASMODE>
__global__ __launch_bounds__(256) void mfma_gemm_k(
    const float* __restrict__ A, const float* __restrict__ B,
    const float* __restrict__ bias, float* __restrict__ C,
    int Kd, int lda, int ldb, int ldc, long long zB, long long zC)
{
  __shared__ short Ah[4 * 64 * 8];
  __shared__ short Al[4 * 64 * 8];
  __shared__ short Bh[4 * 64 * 8];
  __shared__ short Bl[4 * 64 * 8];

  const float* Bz = B + (size_t)blockIdx.z * (size_t)zB;
  float* Cz = C + (size_t)blockIdx.z * (size_t)zC;

  const int tid = threadIdx.x;
  const int lane = tid & 63, w = tid >> 6;
  const int wr = w >> 1, wc = w & 1;
  const int m0 = blockIdx.y * 64, n0 = blockIdx.x * 64;
  const int r16 = lane & 15, kg = lane >> 4;

  f32x4 acc[2][2];
#pragma unroll
  for (int i = 0; i < 2; ++i)
#pragma unroll
    for (int j = 0; j < 2; ++j) acc[i][j] = (f32x4){0.f, 0.f, 0.f, 0.f};

  for (int k0 = 0; k0 < Kd; k0 += 32) {
    {
      int row = tid >> 2, kseg = tid & 3;
      const float* p = A + (size_t)(m0 + row) * lda + k0 + kseg * 8;
      float4 v0 = *(const float4*)p;
      float4 v1 = *(const float4*)(p + 4);
      BfPair q0 = split2(v0.x), q1 = split2(v0.y), q2 = split2(v0.z), q3 = split2(v0.w);
      BfPair q4 = split2(v1.x), q5 = split2(v1.y), q6 = split2(v1.z), q7 = split2(v1.w);
      bf16x8 h = {q0.hi, q1.hi, q2.hi, q3.hi, q4.hi, q5.hi, q6.hi, q7.hi};
      bf16x8 l = {q0.lo, q1.lo, q2.lo, q3.lo, q4.lo, q5.lo, q6.lo, q7.lo};
      int idx = (kseg * 64 + row) * 8;
      *(bf16x8*)&Ah[idx] = h;
      *(bf16x8*)&Al[idx] = l;
    }
    if (BTRANS) {
      int row = tid >> 2, kseg = tid & 3;
      const float* p = Bz + (size_t)(n0 + row) * ldb + k0 + kseg * 8;
      float4 v0 = *(const float4*)p;
      float4 v1 = *(const float4*)(p + 4);
      BfPair q0 = split2(v0.x), q1 = split2(v0.y), q2 = split2(v0.z), q3 = split2(v0.w);
      BfPair q4 = split2(v1.x), q5 = split2(v1.y), q6 = split2(v1.z), q7 = split2(v1.w);
      bf16x8 h = {q0.hi, q1.hi, q2.hi, q3.hi, q4.hi, q5.hi, q6.hi, q7.hi};
      bf16x8 l = {q0.lo, q1.lo, q2.lo, q3.lo, q4.lo, q5.lo, q6.lo, q7.lo};
      int idx = (kseg * 64 + row) * 8;
      *(bf16x8*)&Bh[idx] = h;
      *(bf16x8*)&Bl[idx] = l;
    } else {
      int col = tid & 63, kseg = tid >> 6;
      short hv[8], lv[8];
#pragma unroll
      for (int j = 0; j < 8; ++j) {
        BfPair p = split2(Bz[(size_t)(k0 + kseg * 8 + j) * ldb + n0 + col]);
        hv[j] = p.hi; lv[j] = p.lo;
      }
      bf16x8 h = {hv[0], hv[1], hv[2], hv[3], hv[4], hv[5], hv[6], hv[7]};
      bf16x8 l = {lv[0], lv[1], lv[2], lv[3], lv[4], lv[5], lv[6], lv[7]};
      int idx = (kseg * 64 + col) * 8;
      *(bf16x8*)&Bh[idx] = h;
      *(bf16x8*)&Bl[idx] = l;
    }
    __syncthreads();

    bf16x8 ah[2], al[2], bh[2], bl[2];
#pragma unroll
    for (int f = 0; f < 2; ++f) {
      int ia = (kg * 64 + wr * 32 + f * 16 + r16) * 8;
      int ib = (kg * 64 + wc * 32 + f * 16 + r16) * 8;
      ah[f] = *(const bf16x8*)&Ah[ia];
      al[f] = *(const bf16x8*)&Al[ia];
      bh[f] = *(const bf16x8*)&Bh[ib];
      bl[f] = *(const bf16x8*)&Bl[ib];
    }
#pragma unroll
    for (int fr = 0; fr < 2; ++fr)
#pragma unroll
      for (int fc = 0; fc < 2; ++fc) {
        f32x4 c = acc[fr][fc];
        c = __builtin_amdgcn_mfma_f32_16x16x32_bf16(al[fr], bh[fc], c, 0, 0, 0);
        c = __builtin_amdgcn_mfma_f32_16x16x32_bf16(ah[fr], bl[fc], c, 0, 0, 0);
        c = __builtin_amdgcn_mfma_f32_16x16x32_bf16(ah[fr], bh[fc], c, 0, 0, 0);
        acc[fr][fc] = c;
      }
    __syncthreads();
  }

#pragma unroll
  for (int fr = 0; fr < 2; ++fr)
#pragma unroll
    for (int fc = 0; fc < 2; ++fc) {
      int col = n0 + wc * 32 + fc * 16 + r16;
      float cb = (BIASMODE == 1) ? bias[col] : 0.f;
#pragma unroll
      for (int rr = 0; rr < 4; ++rr) {
        int rw = m0 + wr * 32 + fr * 16 + kg * 4 + rr;
        float rb = (BIASMODE == 2) ? bias[rw] : 0.f;
        Cz[(size_t)rw * ldc + col] = acc[fr][fc][rr] + cb + rb;
      }
    }
}

// kn[b*16+h][c] = 1 / max(||Kc[b, c, h*64 : +64]||, 1e-12)   (fp64)
__global__ __launch_bounds__(256) void kn_k2(const float* __restrict__ Kc,
                                             double* __restrict__ kn)
{
  int idx = (int)blockIdx.x * 256 + (int)threadIdx.x;
  int c = idx & 1023;
  int p = idx >> 10;
  int b = p >> 4, h = p & 15;
  const float* row = Kc + ((size_t)(b * 1024 + c)) * 1024 + h * 64;
  double s = 0.0;
  for (int d = 0; d < 64; ++d) { double v = (double)row[d]; s += v * v; }
  kn[(size_t)p * 1024 + c] = 1.0 / fmax(sqrt(s), 1e-12);
}

// Fused exact top-64 + softmax + PV (bit-frozen, R5-validated).
__global__ __launch_bounds__(256) void topk_attn_k(
    const double* __restrict__ dotb, const double* __restrict__ kn,
    const float* __restrict__ Vc, float* __restrict__ attnout, int group_base)
{
  __shared__ int sC[4][64];
  __shared__ float sD[4][64];

  const int lane = threadIdx.x & 63, wv = threadIdx.x >> 6;
  const int g = (int)blockIdx.x >> 8;
  const int t = ((int)blockIdx.x & 255) * 4 + wv;
  const int pair = group_base + g;
  const int bb = pair >> 4, hh = pair & 15;

  const double* drow = dotb + ((size_t)g * Tn + t) * (size_t)Cn;
  const double* knr  = kn + ((size_t)(bb * Hn + hh)) * Cn;

  double dv[16];
  unsigned long long u[16];
#pragma unroll
  for (int j = 0; j < 8; ++j) {
    double2 dd = *(const double2*)(drow + j * 128 + 2 * lane);
    double2 kk = *(const double2*)(knr  + j * 128 + 2 * lane);
    dv[2 * j] = dd.x; dv[2 * j + 1] = dd.y;
    u[2 * j]     = mapd(dd.x * kk.x);
    u[2 * j + 1] = mapd(dd.y * kk.y);
  }
  unsigned hi[16];
#pragma unroll
  for (int i = 0; i < 16; ++i) hi[i] = (unsigned)(u[i] >> 32);

  unsigned TH = 0;
  for (int bit = 31; bit >= 0; --bit) {
    unsigned Tc = TH | (1u << bit);
    int c = 0;
#pragma unroll
    for (int i = 0; i < 16; ++i) c += (hi[i] >= Tc);
    if (wsumi(c) >= 64) TH = Tc;
  }
  int mhi = 0;
#pragma unroll
  for (int i = 0; i < 16; ++i) mhi += (hi[i] > TH);
  mhi = wsumi(mhi);
  const int need1 = 64 - mhi;
  unsigned TL = 0;
  for (int bit = 31; bit >= 0; --bit) {
    unsigned Tc = TL | (1u << bit);
    int c = 0;
#pragma unroll
    for (int i = 0; i < 16; ++i) c += (hi[i] == TH && (unsigned)u[i] >= Tc);
    if (wsumi(c) >= need1) TL = Tc;
  }
  const unsigned long long V64 = ((unsigned long long)TH << 32) | TL;

  int base = 0;
#pragma unroll
  for (int i = 0; i < 16; ++i) {
    const int cix = 128 * (i >> 1) + 2 * lane + (i & 1);
    bool sel = (u[i] > V64);
    unsigned long long mk = __ballot(sel);
    if (sel) {
      int r = __popcll(mk & ((1ull << lane) - 1ull));
      sC[wv][base + r] = cix;
      sD[wv][base + r] = (float)dv[i];
    }
    base += __popcll(mk);
  }
  const int need = 64 - base;
  unsigned taken = 0;
  for (int r = 0; r < need; ++r) {
    int mn = 0x7fffffff;
#pragma unroll
    for (int i = 0; i < 16; ++i) {
      int cix = 128 * (i >> 1) + 2 * lane + (i & 1);
      if (u[i] == V64 && !((taken >> i) & 1u)) mn = mn < cix ? mn : cix;
    }
    mn = wmini(mn);
#pragma unroll
    for (int i = 0; i < 16; ++i) {
      int cix = 128 * (i >> 1) + 2 * lane + (i & 1);
      if (u[i] == V64 && !((taken >> i) & 1u) && cix == mn) {
        taken |= 1u << i;
        sC[wv][base + r] = mn;
        sD[wv][base + r] = (float)dv[i];
      }
    }
  }
  __syncthreads();

  int ck = sC[wv][lane];
  float sc = sD[wv][lane] * 0.125f;
  float mx = wfmax(sc);
  float w = expf(sc - mx);
  float sw = wfsum(w);
  w /= sw;

  const float* Vb = Vc + (size_t)bb * ((size_t)Cn * 1024) + hh * 64 + lane;
  float acc = 0.f;
#pragma unroll 4
  for (int k = 0; k < 64; ++k) {
    int c = __shfl(ck, k);
    float wk = __shfl(w, k);
    acc = fmaf(wk, Vb[(size_t)c * 1024], acc);
  }
  attnout[((size_t)(bb * Tn + t)) * 1024 + hh * 64 + lane] = acc;
}

// ---------------------------------------------------------------------------
extern "C" void kernel_launch(void* const* d_in, const int* in_sizes, int n_in,
                              void* d_out, int out_size, void* d_ws, size_t ws_size,
                              hipStream_t stream)
{
  const float* x  = (const float*)d_in[0];
  const float* Wq = (const float*)d_in[1];
  const float* bq = (const float*)d_in[2];
  const float* Wk = (const float*)d_in[3];
  const float* bk = (const float*)d_in[4];
  const float* Wv = (const float*)d_in[5];
  const float* bv = (const float*)d_in[6];
  const float* Wo = (const float*)d_in[7];
  const float* bo = (const float*)d_in[8];
  const float* Wc = (const float*)d_in[9];
  const float* bc = (const float*)d_in[10];
  float* out = (float*)d_out;

  const size_t NE = (size_t)2048 * 1024;
  const size_t M1 = (size_t)1024 * 1024;
  float* Q   = (float*)d_ws;
  float* Kf  = Q + NE;
  float* Vf  = Kf + NE;
  float* Kc  = Vf + NE;
  float* Vc  = Kc + NE;
  float* at  = Vc + NE;
  double* kn = (double*)(at + NE);
  double* tail = kn + 32768;

  const size_t fixedB = 6 * NE * 4 + 32768 * 8;
  const size_t dotPairB = (size_t)Tn * Cn * 8;   // 8 MiB per (b,h) pair
  if (ws_size < fixedB) return;

  size_t rem = ws_size - fixedB;
  double* dotp; int G;
  if      (rem >= 8 * dotPairB) { G = 8; dotp = tail; }
  else if (rem >= 4 * dotPairB) { G = 4; dotp = tail; }
  else if (rem >= 2 * dotPairB) { G = 2; dotp = tail; }
  else { G = 2; dotp = (double*)Kf; }  // Kf+Vf dead by then (16 MiB)

  dim3 blk(256, 1, 1);

  // Selection-path projections (probed f64-MFMA, padded LDS)
  f64sel_k<float, true, 1, false><<<dim3(16, 32, 1), blk, 0, stream>>>(
      x, Wq, bq, Q, 1024, 1024, 1024, 1024, 0, 0, 0);
  f64sel_k<float, true, 1, false><<<dim3(16, 32, 1), blk, 0, stream>>>(
      x, Wk, bk, Kf, 1024, 1024, 1024, 1024, 0, 0, 0);
  // Value-path V projection (R9-validated)
  mfma_gemm_k<true, 1><<<dim3(16, 32, 1), blk, 0, stream>>>(
      x, Wv, bv, Vf, 1024, 1024, 1024, 1024, 0, 0);

  // Compress: Kc (f64-MFMA), Vc (R9 MFMA), z = batch
  f64sel_k<float, false, 2, false><<<dim3(16, 16, 2), blk, 0, stream>>>(
      Wc, Kf, bc, Kc, 1024, 1024, 1024, 1024, (long long)M1, (long long)M1, 0);
  mfma_gemm_k<false, 2><<<dim3(16, 16, 2), blk, 0, stream>>>(
      Wc, Vf, bc, Vc, 1024, 1024, 1024, 1024, (long long)M1, (long long)M1);

  kn_k2<<<dim3(128), blk, 0, stream>>>(Kc, kn);

  // Dot planes (f64-MFMA SIM) + fused topk/softmax/PV
  for (int gb = 0; gb < 32; gb += G) {
    f64sel_k<double, true, 0, true><<<dim3(16, 16, G), blk, 0, stream>>>(
        Q, Kc, nullptr, dotp, 64, 1024, 1024, 1024, 0, 0, gb);
    topk_attn_k<<<dim3(256 * G), blk, 0, stream>>>(dotp, kn, Vc, at, gb);
  }

  // Output projection (R9-validated)
  mfma_gemm_k<true, 1><<<dim3(16, 32, 1), blk, 0, stream>>>(
      at, Wo, bo, out, 1024, 1024, 1024, 1024, 0, 0);
}

// Round 15
// 856.844 us; speedup vs baseline: 14.9113x; 1.0380x over previous
//
#include <hip/hip_runtime.h>
#include <type_traits>

// ---------------------------------------------------------------------------
// CSAAttention — round 15 = round 14 structure with PIPELINED GEMMs:
//   f64sel_k: BK 16->32 + register prefetch (global->reg while MFMA runs).
//   mfma_gemm_k: register prefetch, same BK=32.
//   MFMA sequences per accumulator are unchanged (ascending k) -> all
//   pipeline values BIT-IDENTICAL to R12/R14; absmax must stay 0.00390625.
//   kn / topk / launch structure: R14 verbatim.
// ---------------------------------------------------------------------------

#define DEVI __device__ __forceinline__

constexpr int Tn = 1024;
constexpr int Cn = 1024;
constexpr int Hn = 16;

typedef short bf16x8 __attribute__((ext_vector_type(8)));
typedef float f32x4 __attribute__((ext_vector_type(4)));
typedef double f64x4 __attribute__((ext_vector_type(4)));

DEVI int wsumi(int v)   { for (int m = 1; m < 64; m <<= 1) v += __shfl_xor(v, m); return v; }
DEVI int wmini(int v)   { for (int m = 1; m < 64; m <<= 1) { int o = __shfl_xor(v, m); v = o < v ? o : v; } return v; }
DEVI float wfmax(float v){ for (int m = 1; m < 64; m <<= 1) v = fmaxf(v, __shfl_xor(v, m)); return v; }
DEVI float wfsum(float v){ for (int m = 1; m < 64; m <<= 1) v += __shfl_xor(v, m); return v; }

DEVI unsigned long long mapd(double x) {  // monotone fp64 -> uint64
  unsigned long long b = (unsigned long long)__double_as_longlong(x);
  return (b >> 63) ? ~b : (b | 0x8000000000000000ull);
}

DEVI unsigned short f2bf_rne(float x) {
  unsigned u = __float_as_uint(x);
  u += 0x7fffu + ((u >> 16) & 1u);
  return (unsigned short)(u >> 16);
}
struct BfPair { short hi, lo; };
DEVI BfPair split2(float x) {
  unsigned short h = f2bf_rne(x);
  float hf = __uint_as_float(((unsigned)h) << 16);
  BfPair r;
  r.hi = (short)h;
  r.lo = (short)f2bf_rne(x - hf);
  return r;
}

// ---------------------------------------------------------------------------
// Selection-path fp64 GEMM, probed f64-MFMA, BK=32 + register prefetch.
// Per-element k-slice order unchanged (ascending) -> bit-identical to R12.
// C = A * op(B) (+bias). Tile 64x64, 4 waves (2x2 of 32x32).
// SIM: per-z (b,h) slices of Q/Kc -> fp64 dot plane (OUTT=double).
// ---------------------------------------------------------------------------
template <typename OUTT, bool BTRANS, int BIASMODE, bool SIM>
__global__ __launch_bounds__(256) void f64sel_k(
    const float* __restrict__ A, const float* __restrict__ B,
    const float* __restrict__ bias, OUTT* __restrict__ C,
    int Kd, int lda, int ldb, int ldc,
    long long zB, long long zC, int group_base)
{
  __shared__ float As[32][72];
  __shared__ float Bs[32][72];

  size_t offA = 0, offB = 0, offC = 0;
  if (SIM) {
    int pair = group_base + (int)blockIdx.z;
    int bb = pair >> 4, hh = pair & 15;
    offA = ((size_t)bb * Tn) * (size_t)lda + (size_t)hh * 64;
    offB = ((size_t)bb * Cn) * (size_t)ldb + (size_t)hh * 64;
    offC = (size_t)blockIdx.z * (size_t)Tn * (size_t)ldc;
  } else {
    offB = (size_t)blockIdx.z * (size_t)zB;
    offC = (size_t)blockIdx.z * (size_t)zC;
  }
  const float* Ab = A + offA;
  const float* Bb = B + offB;
  OUTT* Cb = C + offC;

  const int tid = threadIdx.x;
  const int lane = tid & 63, w = tid >> 6;
  const int wr = w >> 1, wc = w & 1;
  const int l15 = lane & 15, l4 = lane >> 4;
  const int m0 = blockIdx.y * 64, n0 = blockIdx.x * 64;

  // runtime layout probe (wave-uniform) — R12-validated
  f64x4 zz = {0.0, 0.0, 0.0, 0.0};
  f64x4 p1 = __builtin_amdgcn_mfma_f64_16x16x4f64(1.0, (double)l15, zz, 0, 0, 0);
  f64x4 p2 = __builtin_amdgcn_mfma_f64_16x16x4f64((double)l15, 1.0, zz, 0, 0, 0);
  int a1 = 1, b1 = 1, c1 = 1, a2 = 1, b2 = 1, c2 = 1;
#pragma unroll
  for (int rr = 0; rr < 4; ++rr) {
    a1 &= (p1[rr] == 4.0 * l15);
    b1 &= (p1[rr] == 4.0 * (l4 * 4 + rr));
    c1 &= (p1[rr] == 4.0 * (l4 + 4 * rr));
    a2 &= (p2[rr] == 4.0 * (l4 * 4 + rr));
    b2 &= (p2[rr] == 4.0 * (l4 + 4 * rr));
    c2 &= (p2[rr] == 4.0 * l15);
  }
  a1 = __all(a1); b1 = __all(b1); c1 = __all(c1);
  a2 = __all(a2); b2 = __all(b2); c2 = __all(c2);
  int dmap = 0, useM = 1;
  if      (a1 && a2) dmap = 0;
  else if (a1 && b2) dmap = 1;
  else if (b1 && c2) dmap = 2;
  else if (c1 && c2) dmap = 3;
  else useM = 0;

  f64x4 acc[2][2];
#pragma unroll
  for (int i = 0; i < 2; ++i)
#pragma unroll
    for (int j = 0; j < 2; ++j) acc[i][j] = (f64x4){0.0, 0.0, 0.0, 0.0};

  // staging indices
  const int sm = tid >> 2, skf = tid & 3;           // A / B-trans rows
  const int bkl = tid >> 4, bnf = tid & 15;         // B non-trans

  const int nT = Kd >> 5;
  float4 a0_, a1_, b0_, b1_;
  {  // preload tile 0
    a0_ = *(const float4*)(Ab + (size_t)(m0 + sm) * lda + 4 * skf);
    a1_ = *(const float4*)(Ab + (size_t)(m0 + sm) * lda + 16 + 4 * skf);
    if (BTRANS) {
      b0_ = *(const float4*)(Bb + (size_t)(n0 + sm) * ldb + 4 * skf);
      b1_ = *(const float4*)(Bb + (size_t)(n0 + sm) * ldb + 16 + 4 * skf);
    } else {
      b0_ = *(const float4*)(Bb + (size_t)bkl * ldb + n0 + 4 * bnf);
      b1_ = *(const float4*)(Bb + (size_t)(16 + bkl) * ldb + n0 + 4 * bnf);
    }
  }

  for (int kt = 0; kt < nT; ++kt) {
    // write prefetched tile to LDS
    As[4 * skf + 0][sm] = a0_.x; As[4 * skf + 1][sm] = a0_.y;
    As[4 * skf + 2][sm] = a0_.z; As[4 * skf + 3][sm] = a0_.w;
    As[16 + 4 * skf + 0][sm] = a1_.x; As[16 + 4 * skf + 1][sm] = a1_.y;
    As[16 + 4 * skf + 2][sm] = a1_.z; As[16 + 4 * skf + 3][sm] = a1_.w;
    if (BTRANS) {
      Bs[4 * skf + 0][sm] = b0_.x; Bs[4 * skf + 1][sm] = b0_.y;
      Bs[4 * skf + 2][sm] = b0_.z; Bs[4 * skf + 3][sm] = b0_.w;
      Bs[16 + 4 * skf + 0][sm] = b1_.x; Bs[16 + 4 * skf + 1][sm] = b1_.y;
      Bs[16 + 4 * skf + 2][sm] = b1_.z; Bs[16 + 4 * skf + 3][sm] = b1_.w;
    } else {
      *(float4*)&Bs[bkl][4 * bnf] = b0_;
      *(float4*)&Bs[16 + bkl][4 * bnf] = b1_;
    }
    __syncthreads();

    // prefetch next tile into regs (overlaps MFMA below)
    if (kt + 1 < nT) {
      int k0 = (kt + 1) * 32;
      a0_ = *(const float4*)(Ab + (size_t)(m0 + sm) * lda + k0 + 4 * skf);
      a1_ = *(const float4*)(Ab + (size_t)(m0 + sm) * lda + k0 + 16 + 4 * skf);
      if (BTRANS) {
        b0_ = *(const float4*)(Bb + (size_t)(n0 + sm) * ldb + k0 + 4 * skf);
        b1_ = *(const float4*)(Bb + (size_t)(n0 + sm) * ldb + k0 + 16 + 4 * skf);
      } else {
        b0_ = *(const float4*)(Bb + (size_t)(k0 + bkl) * ldb + n0 + 4 * bnf);
        b1_ = *(const float4*)(Bb + (size_t)(k0 + 16 + bkl) * ldb + n0 + 4 * bnf);
      }
    }

    if (useM) {
#pragma unroll
      for (int kq = 0; kq < 8; ++kq) {
        int kk = kq * 4 + l4;
        double a0  = (double)As[kk][wr * 32 + l15];
        double a1v = (double)As[kk][wr * 32 + 16 + l15];
        double b0  = (double)Bs[kk][wc * 32 + l15];
        double b1v = (double)Bs[kk][wc * 32 + 16 + l15];
        acc[0][0] = __builtin_amdgcn_mfma_f64_16x16x4f64(a0,  b0,  acc[0][0], 0, 0, 0);
        acc[0][1] = __builtin_amdgcn_mfma_f64_16x16x4f64(a0,  b1v, acc[0][1], 0, 0, 0);
        acc[1][0] = __builtin_amdgcn_mfma_f64_16x16x4f64(a1v, b0,  acc[1][0], 0, 0, 0);
        acc[1][1] = __builtin_amdgcn_mfma_f64_16x16x4f64(a1v, b1v, acc[1][1], 0, 0, 0);
      }
    } else {
#pragma unroll
      for (int k = 0; k < 32; ++k) {
        double bv0 = (double)Bs[k][wc * 32 + l15];
        double bv1 = (double)Bs[k][wc * 32 + 16 + l15];
#pragma unroll
        for (int fr = 0; fr < 2; ++fr)
#pragma unroll
          for (int rr = 0; rr < 4; ++rr) {
            double av = (double)As[k][wr * 32 + fr * 16 + l4 * 4 + rr];
            acc[fr][0][rr] += av * bv0;
            acc[fr][1][rr] += av * bv1;
          }
      }
    }
    __syncthreads();
  }

  // epilogue (frozen formula: fp64->fp32 cast, then fp32 bias adds)
#pragma unroll
  for (int fr = 0; fr < 2; ++fr)
#pragma unroll
    for (int fc = 0; fc < 2; ++fc)
#pragma unroll
      for (int rr = 0; rr < 4; ++rr) {
        int ri, ci;
        if (!useM || dmap == 0) { ri = l4 * 4 + rr; ci = l15; }
        else if (dmap == 1)     { ri = l4 + 4 * rr; ci = l15; }
        else if (dmap == 2)     { ri = l15; ci = l4 * 4 + rr; }
        else                    { ri = l15; ci = l4 + 4 * rr; }
        int row = m0 + wr * 32 + fr * 16 + ri;
        int col = n0 + wc * 32 + fc * 16 + ci;
        double v = acc[fr][fc][rr];
        if constexpr (std::is_same<OUTT, double>::value) {
          Cb[(size_t)row * ldc + col] = v;
        } else {
          float s = (float)v;
          float cb = (BIASMODE == 1) ? bias[col] : 0.f;
          float rb = (BIASMODE == 2) ? bias[row] : 0.f;
          ((float*)Cb)[(size_t)row * ldc + col] = s + cb + rb;
        }
      }
}

// ---------------------------------------------------------------------------
// Value-path MFMA GEMM with register prefetch (same BK=32, same MFMA order
// as the R9-validated kernel -> bit-identical outputs).
// ---------------------------------------------------------------------------
template <bool BTRANS, int BIASMODE>
__global__ __launch_bounds__(256) void mfma_gemm_k(
    const float* __restrict__ A, const float* __restrict__ B,
    const float* __restrict__ bias, float* __restrict__ C,
    int Kd, int lda, int ldb, int ldc, long long zB, long long zC)
{
  __shared__ short Ah[4 * 64 * 8];
  __shared__ short Al[4 * 64 * 8];
  __shared__ short Bh[4 * 64 * 8];
  __shared__ short Bl[4 * 64 * 8];

  const float* Bz = B + (size_t)blockIdx.z * (size_t)zB;
  float* Cz = C + (size_t)blockIdx.z * (size_t)zC;

  const int tid = threadIdx.x;
  const int lane = tid & 63, w = tid >> 6;
  const int wr = w >> 1, wc = w & 1;
  const int m0 = blockIdx.y * 64, n0 = blockIdx.x * 64;
  const int r16 = lane & 15, kg = lane >> 4;

  f32x4 acc[2][2];
#pragma unroll
  for (int i = 0; i < 2; ++i)
#pragma unroll
    for (int j = 0; j < 2; ++j) acc[i][j] = (f32x4){0.f, 0.f, 0.f, 0.f};

  const int row = tid >> 2, kseg = tid & 3;       // A / B-trans staging
  const int gcol = tid & 63, gks = tid >> 6;      // B non-trans staging

  const int nT = Kd >> 5;
  float4 pa0, pa1, pb0, pb1;
  float gb[8];
  {  // preload tile 0
    pa0 = *(const float4*)(A + (size_t)(m0 + row) * lda + kseg * 8);
    pa1 = *(const float4*)(A + (size_t)(m0 + row) * lda + kseg * 8 + 4);
    if (BTRANS) {
      pb0 = *(const float4*)(Bz + (size_t)(n0 + row) * ldb + kseg * 8);
      pb1 = *(const float4*)(Bz + (size_t)(n0 + row) * ldb + kseg * 8 + 4);
    } else {
#pragma unroll
      for (int j = 0; j < 8; ++j)
        gb[j] = Bz[(size_t)(gks * 8 + j) * ldb + n0 + gcol];
    }
  }

  for (int kt = 0; kt < nT; ++kt) {
    {  // split prefetched A and write to LDS
      BfPair q0 = split2(pa0.x), q1 = split2(pa0.y), q2 = split2(pa0.z), q3 = split2(pa0.w);
      BfPair q4 = split2(pa1.x), q5 = split2(pa1.y), q6 = split2(pa1.z), q7 = split2(pa1.w);
      bf16x8 h = {q0.hi, q1.hi, q2.hi, q3.hi, q4.hi, q5.hi, q6.hi, q7.hi};
      bf16x8 l = {q0.lo, q1.lo, q2.lo, q3.lo, q4.lo, q5.lo, q6.lo, q7.lo};
      int idx = (kseg * 64 + row) * 8;
      *(bf16x8*)&Ah[idx] = h;
      *(bf16x8*)&Al[idx] = l;
    }
    if (BTRANS) {
      BfPair q0 = split2(pb0.x), q1 = split2(pb0.y), q2 = split2(pb0.z), q3 = split2(pb0.w);
      BfPair q4 = split2(pb1.x), q5 = split2(pb1.y), q6 = split2(pb1.z), q7 = split2(pb1.w);
      bf16x8 h = {q0.hi, q1.hi, q2.hi, q3.hi, q4.hi, q5.hi, q6.hi, q7.hi};
      bf16x8 l = {q0.lo, q1.lo, q2.lo, q3.lo, q4.lo, q5.lo, q6.lo, q7.lo};
      int idx = (kseg * 64 + row) * 8;
      *(bf16x8*)&Bh[idx] = h;
      *(bf16x8*)&Bl[idx] = l;
    } else {
      short hv[8], lv[8];
#pragma unroll
      for (int j = 0; j < 8; ++j) {
        BfPair p = split2(gb[j]);
        hv[j] = p.hi; lv[j] = p.lo;
      }
      bf16x8 h = {hv[0], hv[1], hv[2], hv[3], hv[4], hv[5], hv[6], hv[7]};
      bf16x8 l = {lv[0], lv[1], lv[2], lv[3], lv[4], lv[5], lv[6], lv[7]};
      int idx = (gks * 64 + gcol) * 8;
      *(bf16x8*)&Bh[idx] = h;
      *(bf16x8*)&Bl[idx] = l;
    }
    __syncthreads();

    // prefetch next tile into regs (overlaps MFMA below)
    if (kt + 1 < nT) {
      int k0 = (kt + 1) * 32;
      pa0 = *(const float4*)(A + (size_t)(m0 + row) * lda + k0 + kseg * 8);
      pa1 = *(const float4*)(A + (size_t)(m0 + row) * lda + k0 + kseg * 8 + 4);
      if (BTRANS) {
        pb0 = *(const float4*)(Bz + (size_t)(n0 + row) * ldb + k0 + kseg * 8);
        pb1 = *(const float4*)(Bz + (size_t)(n0 + row) * ldb + k0 + kseg * 8 + 4);
      } else {
#pragma unroll
        for (int j = 0; j < 8; ++j)
          gb[j] = Bz[(size_t)(k0 + gks * 8 + j) * ldb + n0 + gcol];
      }
    }

    bf16x8 ah[2], al[2], bh[2], bl[2];
#pragma unroll
    for (int f = 0; f < 2; ++f) {
      int ia = (kg * 64 + wr * 32 + f * 16 + r16) * 8;
      int ib = (kg * 64 + wc * 32 + f * 16 + r16) * 8;
      ah[f] = *(const bf16x8*)&Ah[ia];
      al[f] = *(const bf16x8*)&Al[ia];
      bh[f] = *(const bf16x8*)&Bh[ib];
      bl[f] = *(const bf16x8*)&Bl[ib];
    }
#pragma unroll
    for (int fr = 0; fr < 2; ++fr)
#pragma unroll
      for (int fc = 0; fc < 2; ++fc) {
        f32x4 c = acc[fr][fc];
        c = __builtin_amdgcn_mfma_f32_16x16x32_bf16(al[fr], bh[fc], c, 0, 0, 0);
        c = __builtin_amdgcn_mfma_f32_16x16x32_bf16(ah[fr], bl[fc], c, 0, 0, 0);
        c = __builtin_amdgcn_mfma_f32_16x16x32_bf16(ah[fr], bh[fc], c, 0, 0, 0);
        acc[fr][fc] = c;
      }
    __syncthreads();
  }

#pragma unroll
  for (int fr = 0; fr < 2; ++fr)
#pragma unroll
    for (int fc = 0; fc < 2; ++fc) {
      int col = n0 + wc * 32 + fc * 16 + r16;
      float cb = (BIASMODE == 1) ? bias[col] : 0.f;
#pragma unroll
      for (int rr = 0; rr < 4; ++rr) {
        int rw = m0 + wr * 32 + fr * 16 + kg * 4 + rr;
        float rb = (BIASMODE == 2) ? bias[rw] : 0.f;
        Cz[(size_t)rw * ldc + col] = acc[fr][fc][rr] + cb + rb;
      }
    }
}

// kn[b*16+h][c] = 1 / max(||Kc[b, c, h*64 : +64]||, 1e-12)   (fp64)
__global__ __launch_bounds__(256) void kn_k2(const float* __restrict__ Kc,
                                             double* __restrict__ kn)
{
  int idx = (int)blockIdx.x * 256 + (int)threadIdx.x;
  int c = idx & 1023;
  int p = idx >> 10;
  int b = p >> 4, h = p & 15;
  const float* row = Kc + ((size_t)(b * 1024 + c)) * 1024 + h * 64;
  double s = 0.0;
  for (int d = 0; d < 64; ++d) { double v = (double)row[d]; s += v * v; }
  kn[(size_t)p * 1024 + c] = 1.0 / fmax(sqrt(s), 1e-12);
}

// Fused exact top-64 + softmax + PV (bit-frozen, R5-validated).
__global__ __launch_bounds__(256) void topk_attn_k(
    const double* __restrict__ dotb, const double* __restrict__ kn,
    const float* __restrict__ Vc, float* __restrict__ attnout, int group_base)
{
  __shared__ int sC[4][64];
  __shared__ float sD[4][64];

  const int lane = threadIdx.x & 63, wv = threadIdx.x >> 6;
  const int g = (int)blockIdx.x >> 8;
  const int t = ((int)blockIdx.x & 255) * 4 + wv;
  const int pair = group_base + g;
  const int bb = pair >> 4, hh = pair & 15;

  const double* drow = dotb + ((size_t)g * Tn + t) * (size_t)Cn;
  const double* knr  = kn + ((size_t)(bb * Hn + hh)) * Cn;

  double dv[16];
  unsigned long long u[16];
#pragma unroll
  for (int j = 0; j < 8; ++j) {
    double2 dd = *(const double2*)(drow + j * 128 + 2 * lane);
    double2 kk = *(const double2*)(knr  + j * 128 + 2 * lane);
    dv[2 * j] = dd.x; dv[2 * j + 1] = dd.y;
    u[2 * j]     = mapd(dd.x * kk.x);
    u[2 * j + 1] = mapd(dd.y * kk.y);
  }
  unsigned hi[16];
#pragma unroll
  for (int i = 0; i < 16; ++i) hi[i] = (unsigned)(u[i] >> 32);

  unsigned TH = 0;
  for (int bit = 31; bit >= 0; --bit) {
    unsigned Tc = TH | (1u << bit);
    int c = 0;
#pragma unroll
    for (int i = 0; i < 16; ++i) c += (hi[i] >= Tc);
    if (wsumi(c) >= 64) TH = Tc;
  }
  int mhi = 0;
#pragma unroll
  for (int i = 0; i < 16; ++i) mhi += (hi[i] > TH);
  mhi = wsumi(mhi);
  const int need1 = 64 - mhi;
  unsigned TL = 0;
  for (int bit = 31; bit >= 0; --bit) {
    unsigned Tc = TL | (1u << bit);
    int c = 0;
#pragma unroll
    for (int i = 0; i < 16; ++i) c += (hi[i] == TH && (unsigned)u[i] >= Tc);
    if (wsumi(c) >= need1) TL = Tc;
  }
  const unsigned long long V64 = ((unsigned long long)TH << 32) | TL;

  int base = 0;
#pragma unroll
  for (int i = 0; i < 16; ++i) {
    const int cix = 128 * (i >> 1) + 2 * lane + (i & 1);
    bool sel = (u[i] > V64);
    unsigned long long mk = __ballot(sel);
    if (sel) {
      int r = __popcll(mk & ((1ull << lane) - 1ull));
      sC[wv][base + r] = cix;
      sD[wv][base + r] = (float)dv[i];
    }
    base += __popcll(mk);
  }
  const int need = 64 - base;
  unsigned taken = 0;
  for (int r = 0; r < need; ++r) {
    int mn = 0x7fffffff;
#pragma unroll
    for (int i = 0; i < 16; ++i) {
      int cix = 128 * (i >> 1) + 2 * lane + (i & 1);
      if (u[i] == V64 && !((taken >> i) & 1u)) mn = mn < cix ? mn : cix;
    }
    mn = wmini(mn);
#pragma unroll
    for (int i = 0; i < 16; ++i) {
      int cix = 128 * (i >> 1) + 2 * lane + (i & 1);
      if (u[i] == V64 && !((taken >> i) & 1u) && cix == mn) {
        taken |= 1u << i;
        sC[wv][base + r] = mn;
        sD[wv][base + r] = (float)dv[i];
      }
    }
  }
  __syncthreads();

  int ck = sC[wv][lane];
  float sc = sD[wv][lane] * 0.125f;
  float mx = wfmax(sc);
  float w = expf(sc - mx);
  float sw = wfsum(w);
  w /= sw;

  const float* Vb = Vc + (size_t)bb * ((size_t)Cn * 1024) + hh * 64 + lane;
  float acc = 0.f;
#pragma unroll 4
  for (int k = 0; k < 64; ++k) {
    int c = __shfl(ck, k);
    float wk = __shfl(w, k);
    acc = fmaf(wk, Vb[(size_t)c * 1024], acc);
  }
  attnout[((size_t)(bb * Tn + t)) * 1024 + hh * 64 + lane] = acc;
}

// ---------------------------------------------------------------------------
extern "C" void kernel_launch(void* const* d_in, const int* in_sizes, int n_in,
                              void* d_out, int out_size, void* d_ws, size_t ws_size,
                              hipStream_t stream)
{
  const float* x  = (const float*)d_in[0];
  const float* Wq = (const float*)d_in[1];
  const float* bq = (const float*)d_in[2];
  const float* Wk = (const float*)d_in[3];
  const float* bk = (const float*)d_in[4];
  const float* Wv = (const float*)d_in[5];
  const float* bv = (const float*)d_in[6];
  const float* Wo = (const float*)d_in[7];
  const float* bo = (const float*)d_in[8];
  const float* Wc = (const float*)d_in[9];
  const float* bc = (const float*)d_in[10];
  float* out = (float*)d_out;

  const size_t NE = (size_t)2048 * 1024;
  const size_t M1 = (size_t)1024 * 1024;
  float* Q   = (float*)d_ws;
  float* Kf  = Q + NE;
  float* Vf  = Kf + NE;
  float* Kc  = Vf + NE;
  float* Vc  = Kc + NE;
  float* at  = Vc + NE;
  double* kn = (double*)(at + NE);
  double* tail = kn + 32768;

  const size_t fixedB = 6 * NE * 4 + 32768 * 8;
  const size_t dotPairB = (size_t)Tn * Cn * 8;   // 8 MiB per (b,h) pair
  if (ws_size < fixedB) return;

  size_t rem = ws_size - fixedB;
  double* dotp; int G;
  if      (rem >= 8 * dotPairB) { G = 8; dotp = tail; }
  else if (rem >= 4 * dotPairB) { G = 4; dotp = tail; }
  else if (rem >= 2 * dotPairB) { G = 2; dotp = tail; }
  else { G = 2; dotp = (double*)Kf; }  // Kf+Vf dead by then (16 MiB)

  dim3 blk(256, 1, 1);

  // Selection-path projections (probed f64-MFMA, pipelined)
  f64sel_k<float, true, 1, false><<<dim3(16, 32, 1), blk, 0, stream>>>(
      x, Wq, bq, Q, 1024, 1024, 1024, 1024, 0, 0, 0);
  f64sel_k<float, true, 1, false><<<dim3(16, 32, 1), blk, 0, stream>>>(
      x, Wk, bk, Kf, 1024, 1024, 1024, 1024, 0, 0, 0);
  // Value-path V projection (pipelined)
  mfma_gemm_k<true, 1><<<dim3(16, 32, 1), blk, 0, stream>>>(
      x, Wv, bv, Vf, 1024, 1024, 1024, 1024, 0, 0);

  // Compress: Kc (f64-MFMA), Vc (value MFMA), z = batch
  f64sel_k<float, false, 2, false><<<dim3(16, 16, 2), blk, 0, stream>>>(
      Wc, Kf, bc, Kc, 1024, 1024, 1024, 1024, (long long)M1, (long long)M1, 0);
  mfma_gemm_k<false, 2><<<dim3(16, 16, 2), blk, 0, stream>>>(
      Wc, Vf, bc, Vc, 1024, 1024, 1024, 1024, (long long)M1, (long long)M1);

  kn_k2<<<dim3(128), blk, 0, stream>>>(Kc, kn);

  // Dot planes (f64-MFMA SIM, pipelined) + fused topk/softmax/PV
  for (int gb = 0; gb < 32; gb += G) {
    f64sel_k<double, true, 0, true><<<dim3(16, 16, G), blk, 0, stream>>>(
        Q, Kc, nullptr, dotp, 64, 1024, 1024, 1024, 0, 0, gb);
    topk_attn_k<<<dim3(256 * G), blk, 0, stream>>>(dotp, kn, Vc, at, gb);
  }

  // Output projection (pipelined)
  mfma_gemm_k<true, 1><<<dim3(16, 32, 1), blk, 0, stream>>>(
      at, Wo, bo, out, 1024, 1024, 1024, 1024, 0, 0);
}

// Round 16
// 812.484 us; speedup vs baseline: 15.7254x; 1.0546x over previous
//
#include <hip/hip_runtime.h>
#include <type_traits>

// ---------------------------------------------------------------------------
// CSAAttention — round 16 = round 15 + LDS DOUBLE-BUFFER (1 barrier/tile)
//   in both GEMM families, Q+K merged into one z=2 dispatch (DUAL mode),
//   G tiers extended to 16/32. MFMA order per accumulator unchanged ->
//   bit-identical; absmax must stay exactly 0.00390625.
// ---------------------------------------------------------------------------

#define DEVI __device__ __forceinline__

constexpr int Tn = 1024;
constexpr int Cn = 1024;
constexpr int Hn = 16;

typedef short bf16x8 __attribute__((ext_vector_type(8)));
typedef float f32x4 __attribute__((ext_vector_type(4)));
typedef double f64x4 __attribute__((ext_vector_type(4)));

DEVI int wsumi(int v)   { for (int m = 1; m < 64; m <<= 1) v += __shfl_xor(v, m); return v; }
DEVI int wmini(int v)   { for (int m = 1; m < 64; m <<= 1) { int o = __shfl_xor(v, m); v = o < v ? o : v; } return v; }
DEVI float wfmax(float v){ for (int m = 1; m < 64; m <<= 1) v = fmaxf(v, __shfl_xor(v, m)); return v; }
DEVI float wfsum(float v){ for (int m = 1; m < 64; m <<= 1) v += __shfl_xor(v, m); return v; }

DEVI unsigned long long mapd(double x) {  // monotone fp64 -> uint64
  unsigned long long b = (unsigned long long)__double_as_longlong(x);
  return (b >> 63) ? ~b : (b | 0x8000000000000000ull);
}

DEVI unsigned short f2bf_rne(float x) {
  unsigned u = __float_as_uint(x);
  u += 0x7fffu + ((u >> 16) & 1u);
  return (unsigned short)(u >> 16);
}
struct BfPair { short hi, lo; };
DEVI BfPair split2(float x) {
  unsigned short h = f2bf_rne(x);
  float hf = __uint_as_float(((unsigned)h) << 16);
  BfPair r;
  r.hi = (short)h;
  r.lo = (short)f2bf_rne(x - hf);
  return r;
}

// ---------------------------------------------------------------------------
// Selection-path fp64 GEMM, probed f64-MFMA, BK=32, DOUBLE-BUFFERED LDS.
// MODE: 0 = z-batch via zB/zC, 1 = SIM (per-(b,h) dot planes), 2 = DUAL
// (z selects {B,bias,C} vs {Bx,biasx,Cx}; A shared). Bit-identical to R12.
// ---------------------------------------------------------------------------
template <typename OUTT, bool BTRANS, int BIASMODE, int MODE>
__global__ __launch_bounds__(256) void f64sel_k(
    const float* __restrict__ A, const float* __restrict__ B,
    const float* __restrict__ Bx, const float* __restrict__ bias,
    const float* __restrict__ biasx, OUTT* __restrict__ C, OUTT* __restrict__ Cx,
    int Kd, int lda, int ldb, int ldc,
    long long zB, long long zC, int group_base)
{
  __shared__ float As[2][32][72];
  __shared__ float Bs[2][32][72];

  const float* Ab = A;
  const float* Bb = B;
  OUTT* Cb = C;
  if (MODE == 1) {
    int pair = group_base + (int)blockIdx.z;
    int bb = pair >> 4, hh = pair & 15;
    Ab = A + ((size_t)bb * Tn) * (size_t)lda + (size_t)hh * 64;
    Bb = B + ((size_t)bb * Cn) * (size_t)ldb + (size_t)hh * 64;
    Cb = C + (size_t)blockIdx.z * (size_t)Tn * (size_t)ldc;
  } else if (MODE == 0) {
    Bb = B + (size_t)blockIdx.z * (size_t)zB;
    Cb = C + (size_t)blockIdx.z * (size_t)zC;
  } else {  // DUAL
    if (blockIdx.z == 1) { Bb = Bx; bias = biasx; Cb = Cx; }
  }

  const int tid = threadIdx.x;
  const int lane = tid & 63, w = tid >> 6;
  const int wr = w >> 1, wc = w & 1;
  const int l15 = lane & 15, l4 = lane >> 4;
  const int m0 = blockIdx.y * 64, n0 = blockIdx.x * 64;

  // runtime layout probe (wave-uniform) — R12-validated
  f64x4 zz = {0.0, 0.0, 0.0, 0.0};
  f64x4 p1 = __builtin_amdgcn_mfma_f64_16x16x4f64(1.0, (double)l15, zz, 0, 0, 0);
  f64x4 p2 = __builtin_amdgcn_mfma_f64_16x16x4f64((double)l15, 1.0, zz, 0, 0, 0);
  int a1 = 1, b1 = 1, c1 = 1, a2 = 1, b2 = 1, c2 = 1;
#pragma unroll
  for (int rr = 0; rr < 4; ++rr) {
    a1 &= (p1[rr] == 4.0 * l15);
    b1 &= (p1[rr] == 4.0 * (l4 * 4 + rr));
    c1 &= (p1[rr] == 4.0 * (l4 + 4 * rr));
    a2 &= (p2[rr] == 4.0 * (l4 * 4 + rr));
    b2 &= (p2[rr] == 4.0 * (l4 + 4 * rr));
    c2 &= (p2[rr] == 4.0 * l15);
  }
  a1 = __all(a1); b1 = __all(b1); c1 = __all(c1);
  a2 = __all(a2); b2 = __all(b2); c2 = __all(c2);
  int dmap = 0, useM = 1;
  if      (a1 && a2) dmap = 0;
  else if (a1 && b2) dmap = 1;
  else if (b1 && c2) dmap = 2;
  else if (c1 && c2) dmap = 3;
  else useM = 0;

  f64x4 acc[2][2];
#pragma unroll
  for (int i = 0; i < 2; ++i)
#pragma unroll
    for (int j = 0; j < 2; ++j) acc[i][j] = (f64x4){0.0, 0.0, 0.0, 0.0};

  const int sm = tid >> 2, skf = tid & 3;           // A / B-trans rows
  const int bkl = tid >> 4, bnf = tid & 15;         // B non-trans

  const int nT = Kd >> 5;
  float4 a0_, a1_, b0_, b1_;

  // helper lambdas (inlined) -----------------------------------------------
  auto LOADT = [&](int k0) {
    a0_ = *(const float4*)(Ab + (size_t)(m0 + sm) * lda + k0 + 4 * skf);
    a1_ = *(const float4*)(Ab + (size_t)(m0 + sm) * lda + k0 + 16 + 4 * skf);
    if (BTRANS) {
      b0_ = *(const float4*)(Bb + (size_t)(n0 + sm) * ldb + k0 + 4 * skf);
      b1_ = *(const float4*)(Bb + (size_t)(n0 + sm) * ldb + k0 + 16 + 4 * skf);
    } else {
      b0_ = *(const float4*)(Bb + (size_t)(k0 + bkl) * ldb + n0 + 4 * bnf);
      b1_ = *(const float4*)(Bb + (size_t)(k0 + 16 + bkl) * ldb + n0 + 4 * bnf);
    }
  };
  auto WRITET = [&](int buf) {
    As[buf][4 * skf + 0][sm] = a0_.x; As[buf][4 * skf + 1][sm] = a0_.y;
    As[buf][4 * skf + 2][sm] = a0_.z; As[buf][4 * skf + 3][sm] = a0_.w;
    As[buf][16 + 4 * skf + 0][sm] = a1_.x; As[buf][16 + 4 * skf + 1][sm] = a1_.y;
    As[buf][16 + 4 * skf + 2][sm] = a1_.z; As[buf][16 + 4 * skf + 3][sm] = a1_.w;
    if (BTRANS) {
      Bs[buf][4 * skf + 0][sm] = b0_.x; Bs[buf][4 * skf + 1][sm] = b0_.y;
      Bs[buf][4 * skf + 2][sm] = b0_.z; Bs[buf][4 * skf + 3][sm] = b0_.w;
      Bs[buf][16 + 4 * skf + 0][sm] = b1_.x; Bs[buf][16 + 4 * skf + 1][sm] = b1_.y;
      Bs[buf][16 + 4 * skf + 2][sm] = b1_.z; Bs[buf][16 + 4 * skf + 3][sm] = b1_.w;
    } else {
      *(float4*)&Bs[buf][bkl][4 * bnf] = b0_;
      *(float4*)&Bs[buf][16 + bkl][4 * bnf] = b1_;
    }
  };

  LOADT(0);
  WRITET(0);
  __syncthreads();

  for (int kt = 0; kt < nT; ++kt) {
    const int cur = kt & 1;
    if (kt + 1 < nT) LOADT((kt + 1) * 32);   // issue loads (overlap MFMA)

    if (useM) {
#pragma unroll
      for (int kq = 0; kq < 8; ++kq) {
        int kk = kq * 4 + l4;
        double a0  = (double)As[cur][kk][wr * 32 + l15];
        double a1v = (double)As[cur][kk][wr * 32 + 16 + l15];
        double b0  = (double)Bs[cur][kk][wc * 32 + l15];
        double b1v = (double)Bs[cur][kk][wc * 32 + 16 + l15];
        acc[0][0] = __builtin_amdgcn_mfma_f64_16x16x4f64(a0,  b0,  acc[0][0], 0, 0, 0);
        acc[0][1] = __builtin_amdgcn_mfma_f64_16x16x4f64(a0,  b1v, acc[0][1], 0, 0, 0);
        acc[1][0] = __builtin_amdgcn_mfma_f64_16x16x4f64(a1v, b0,  acc[1][0], 0, 0, 0);
        acc[1][1] = __builtin_amdgcn_mfma_f64_16x16x4f64(a1v, b1v, acc[1][1], 0, 0, 0);
      }
    } else {
#pragma unroll
      for (int k = 0; k < 32; ++k) {
        double bv0 = (double)Bs[cur][k][wc * 32 + l15];
        double bv1 = (double)Bs[cur][k][wc * 32 + 16 + l15];
#pragma unroll
        for (int fr = 0; fr < 2; ++fr)
#pragma unroll
          for (int rr = 0; rr < 4; ++rr) {
            double av = (double)As[cur][k][wr * 32 + fr * 16 + l4 * 4 + rr];
            acc[fr][0][rr] += av * bv0;
            acc[fr][1][rr] += av * bv1;
          }
      }
    }

    if (kt + 1 < nT) WRITET(cur ^ 1);        // write next tile (other buffer)
    __syncthreads();                          // one barrier per tile
  }

  // epilogue (frozen formula: fp64->fp32 cast, then fp32 bias adds)
#pragma unroll
  for (int fr = 0; fr < 2; ++fr)
#pragma unroll
    for (int fc = 0; fc < 2; ++fc)
#pragma unroll
      for (int rr = 0; rr < 4; ++rr) {
        int ri, ci;
        if (!useM || dmap == 0) { ri = l4 * 4 + rr; ci = l15; }
        else if (dmap == 1)     { ri = l4 + 4 * rr; ci = l15; }
        else if (dmap == 2)     { ri = l15; ci = l4 * 4 + rr; }
        else                    { ri = l15; ci = l4 + 4 * rr; }
        int row = m0 + wr * 32 + fr * 16 + ri;
        int col = n0 + wc * 32 + fc * 16 + ci;
        double v = acc[fr][fc][rr];
        if constexpr (std::is_same<OUTT, double>::value) {
          Cb[(size_t)row * ldc + col] = v;
        } else {
          float s = (float)v;
          float cb = (BIASMODE == 1) ? bias[col] : 0.f;
          float rb = (BIASMODE == 2) ? bias[row] : 0.f;
          ((float*)Cb)[(size_t)row * ldc + col] = s + cb + rb;
        }
      }
}

// ---------------------------------------------------------------------------
// Value-path MFMA GEMM, double-buffered LDS, same MFMA order as R9 ->
// bit-identical outputs.
// ---------------------------------------------------------------------------
template <bool BTRANS, int BIASMODE>
__global__ __launch_bounds__(256) void mfma_gemm_k(
    const float* __restrict__ A, const float* __restrict__ B,
    const float* __restrict__ bias, float* __restrict__ C,
    int Kd, int lda, int ldb, int ldc, long long zB, long long zC)
{
  __shared__ short Ah[2][4 * 64 * 8];
  __shared__ short Al[2][4 * 64 * 8];
  __shared__ short Bh[2][4 * 64 * 8];
  __shared__ short Bl[2][4 * 64 * 8];

  const float* Bz = B + (size_t)blockIdx.z * (size_t)zB;
  float* Cz = C + (size_t)blockIdx.z * (size_t)zC;

  const int tid = threadIdx.x;
  const int lane = tid & 63, w = tid >> 6;
  const int wr = w >> 1, wc = w & 1;
  const int m0 = blockIdx.y * 64, n0 = blockIdx.x * 64;
  const int r16 = lane & 15, kg = lane >> 4;

  f32x4 acc[2][2];
#pragma unroll
  for (int i = 0; i < 2; ++i)
#pragma unroll
    for (int j = 0; j < 2; ++j) acc[i][j] = (f32x4){0.f, 0.f, 0.f, 0.f};

  const int row = tid >> 2, kseg = tid & 3;       // A / B-trans staging
  const int gcol = tid & 63, gks = tid >> 6;      // B non-trans staging

  const int nT = Kd >> 5;
  float4 pa0, pa1, pb0, pb1;
  float gb[8];

  auto LOADT = [&](int k0) {
    pa0 = *(const float4*)(A + (size_t)(m0 + row) * lda + k0 + kseg * 8);
    pa1 = *(const float4*)(A + (size_t)(m0 + row) * lda + k0 + kseg * 8 + 4);
    if (BTRANS) {
      pb0 = *(const float4*)(Bz + (size_t)(n0 + row) * ldb + k0 + kseg * 8);
      pb1 = *(const float4*)(Bz + (size_t)(n0 + row) * ldb + k0 + kseg * 8 + 4);
    } else {
#pragma unroll
      for (int j = 0; j < 8; ++j)
        gb[j] = Bz[(size_t)(k0 + gks * 8 + j) * ldb + n0 + gcol];
    }
  };
  auto WRITET = [&](int buf) {
    {
      BfPair q0 = split2(pa0.x), q1 = split2(pa0.y), q2 = split2(pa0.z), q3 = split2(pa0.w);
      BfPair q4 = split2(pa1.x), q5 = split2(pa1.y), q6 = split2(pa1.z), q7 = split2(pa1.w);
      bf16x8 h = {q0.hi, q1.hi, q2.hi, q3.hi, q4.hi, q5.hi, q6.hi, q7.hi};
      bf16x8 l = {q0.lo, q1.lo, q2.lo, q3.lo, q4.lo, q5.lo, q6.lo, q7.lo};
      int idx = (kseg * 64 + row) * 8;
      *(bf16x8*)&Ah[buf][idx] = h;
      *(bf16x8*)&Al[buf][idx] = l;
    }
    if (BTRANS) {
      BfPair q0 = split2(pb0.x), q1 = split2(pb0.y), q2 = split2(pb0.z), q3 = split2(pb0.w);
      BfPair q4 = split2(pb1.x), q5 = split2(pb1.y), q6 = split2(pb1.z), q7 = split2(pb1.w);
      bf16x8 h = {q0.hi, q1.hi, q2.hi, q3.hi, q4.hi, q5.hi, q6.hi, q7.hi};
      bf16x8 l = {q0.lo, q1.lo, q2.lo, q3.lo, q4.lo, q5.lo, q6.lo, q7.lo};
      int idx = (kseg * 64 + row) * 8;
      *(bf16x8*)&Bh[buf][idx] = h;
      *(bf16x8*)&Bl[buf][idx] = l;
    } else {
      short hv[8], lv[8];
#pragma unroll
      for (int j = 0; j < 8; ++j) {
        BfPair p = split2(gb[j]);
        hv[j] = p.hi; lv[j] = p.lo;
      }
      bf16x8 h = {hv[0], hv[1], hv[2], hv[3], hv[4], hv[5], hv[6], hv[7]};
      bf16x8 l = {lv[0], lv[1], lv[2], lv[3], lv[4], lv[5], lv[6], lv[7]};
      int idx = (gks * 64 + gcol) * 8;
      *(bf16x8*)&Bh[buf][idx] = h;
      *(bf16x8*)&Bl[buf][idx] = l;
    }
  };

  LOADT(0);
  WRITET(0);
  __syncthreads();

  for (int kt = 0; kt < nT; ++kt) {
    const int cur = kt & 1;
    if (kt + 1 < nT) LOADT((kt + 1) * 32);

    bf16x8 ah[2], al[2], bh[2], bl[2];
#pragma unroll
    for (int f = 0; f < 2; ++f) {
      int ia = (kg * 64 + wr * 32 + f * 16 + r16) * 8;
      int ib = (kg * 64 + wc * 32 + f * 16 + r16) * 8;
      ah[f] = *(const bf16x8*)&Ah[cur][ia];
      al[f] = *(const bf16x8*)&Al[cur][ia];
      bh[f] = *(const bf16x8*)&Bh[cur][ib];
      bl[f] = *(const bf16x8*)&Bl[cur][ib];
    }
#pragma unroll
    for (int fr = 0; fr < 2; ++fr)
#pragma unroll
      for (int fc = 0; fc < 2; ++fc) {
        f32x4 c = acc[fr][fc];
        c = __builtin_amdgcn_mfma_f32_16x16x32_bf16(al[fr], bh[fc], c, 0, 0, 0);
        c = __builtin_amdgcn_mfma_f32_16x16x32_bf16(ah[fr], bl[fc], c, 0, 0, 0);
        c = __builtin_amdgcn_mfma_f32_16x16x32_bf16(ah[fr], bh[fc], c, 0, 0, 0);
        acc[fr][fc] = c;
      }

    if (kt + 1 < nT) WRITET(cur ^ 1);
    __syncthreads();
  }

#pragma unroll
  for (int fr = 0; fr < 2; ++fr)
#pragma unroll
    for (int fc = 0; fc < 2; ++fc) {
      int col = n0 + wc * 32 + fc * 16 + r16;
      float cb = (BIASMODE == 1) ? bias[col] : 0.f;
#pragma unroll
      for (int rr = 0; rr < 4; ++rr) {
        int rw = m0 + wr * 32 + fr * 16 + kg * 4 + rr;
        float rb = (BIASMODE == 2) ? bias[rw] : 0.f;
        Cz[(size_t)rw * ldc + col] = acc[fr][fc][rr] + cb + rb;
      }
    }
}

// kn[b*16+h][c] = 1 / max(||Kc[b, c, h*64 : +64]||, 1e-12)   (fp64)
__global__ __launch_bounds__(256) void kn_k2(const float* __restrict__ Kc,
                                             double* __restrict__ kn)
{
  int idx = (int)blockIdx.x * 256 + (int)threadIdx.x;
  int c = idx & 1023;
  int p = idx >> 10;
  int b = p >> 4, h = p & 15;
  const float* row = Kc + ((size_t)(b * 1024 + c)) * 1024 + h * 64;
  double s = 0.0;
  for (int d = 0; d < 64; ++d) { double v = (double)row[d]; s += v * v; }
  kn[(size_t)p * 1024 + c] = 1.0 / fmax(sqrt(s), 1e-12);
}

// Fused exact top-64 + softmax + PV (bit-frozen, R5-validated).
__global__ __launch_bounds__(256) void topk_attn_k(
    const double* __restrict__ dotb, const double* __restrict__ kn,
    const float* __restrict__ Vc, float* __restrict__ attnout, int group_base)
{
  __shared__ int sC[4][64];
  __shared__ float sD[4][64];

  const int lane = threadIdx.x & 63, wv = threadIdx.x >> 6;
  const int g = (int)blockIdx.x >> 8;
  const int t = ((int)blockIdx.x & 255) * 4 + wv;
  const int pair = group_base + g;
  const int bb = pair >> 4, hh = pair & 15;

  const double* drow = dotb + ((size_t)g * Tn + t) * (size_t)Cn;
  const double* knr  = kn + ((size_t)(bb * Hn + hh)) * Cn;

  double dv[16];
  unsigned long long u[16];
#pragma unroll
  for (int j = 0; j < 8; ++j) {
    double2 dd = *(const double2*)(drow + j * 128 + 2 * lane);
    double2 kk = *(const double2*)(knr  + j * 128 + 2 * lane);
    dv[2 * j] = dd.x; dv[2 * j + 1] = dd.y;
    u[2 * j]     = mapd(dd.x * kk.x);
    u[2 * j + 1] = mapd(dd.y * kk.y);
  }
  unsigned hi[16];
#pragma unroll
  for (int i = 0; i < 16; ++i) hi[i] = (unsigned)(u[i] >> 32);

  unsigned TH = 0;
  for (int bit = 31; bit >= 0; --bit) {
    unsigned Tc = TH | (1u << bit);
    int c = 0;
#pragma unroll
    for (int i = 0; i < 16; ++i) c += (hi[i] >= Tc);
    if (wsumi(c) >= 64) TH = Tc;
  }
  int mhi = 0;
#pragma unroll
  for (int i = 0; i < 16; ++i) mhi += (hi[i] > TH);
  mhi = wsumi(mhi);
  const int need1 = 64 - mhi;
  unsigned TL = 0;
  for (int bit = 31; bit >= 0; --bit) {
    unsigned Tc = TL | (1u << bit);
    int c = 0;
#pragma unroll
    for (int i = 0; i < 16; ++i) c += (hi[i] == TH && (unsigned)u[i] >= Tc);
    if (wsumi(c) >= need1) TL = Tc;
  }
  const unsigned long long V64 = ((unsigned long long)TH << 32) | TL;

  int base = 0;
#pragma unroll
  for (int i = 0; i < 16; ++i) {
    const int cix = 128 * (i >> 1) + 2 * lane + (i & 1);
    bool sel = (u[i] > V64);
    unsigned long long mk = __ballot(sel);
    if (sel) {
      int r = __popcll(mk & ((1ull << lane) - 1ull));
      sC[wv][base + r] = cix;
      sD[wv][base + r] = (float)dv[i];
    }
    base += __popcll(mk);
  }
  const int need = 64 - base;
  unsigned taken = 0;
  for (int r = 0; r < need; ++r) {
    int mn = 0x7fffffff;
#pragma unroll
    for (int i = 0; i < 16; ++i) {
      int cix = 128 * (i >> 1) + 2 * lane + (i & 1);
      if (u[i] == V64 && !((taken >> i) & 1u)) mn = mn < cix ? mn : cix;
    }
    mn = wmini(mn);
#pragma unroll
    for (int i = 0; i < 16; ++i) {
      int cix = 128 * (i >> 1) + 2 * lane + (i & 1);
      if (u[i] == V64 && !((taken >> i) & 1u) && cix == mn) {
        taken |= 1u << i;
        sC[wv][base + r] = mn;
        sD[wv][base + r] = (float)dv[i];
      }
    }
  }
  __syncthreads();

  int ck = sC[wv][lane];
  float sc = sD[wv][lane] * 0.125f;
  float mx = wfmax(sc);
  float w = expf(sc - mx);
  float sw = wfsum(w);
  w /= sw;

  const float* Vb = Vc + (size_t)bb * ((size_t)Cn * 1024) + hh * 64 + lane;
  float acc = 0.f;
#pragma unroll 4
  for (int k = 0; k < 64; ++k) {
    int c = __shfl(ck, k);
    float wk = __shfl(w, k);
    acc = fmaf(wk, Vb[(size_t)c * 1024], acc);
  }
  attnout[((size_t)(bb * Tn + t)) * 1024 + hh * 64 + lane] = acc;
}

// ---------------------------------------------------------------------------
extern "C" void kernel_launch(void* const* d_in, const int* in_sizes, int n_in,
                              void* d_out, int out_size, void* d_ws, size_t ws_size,
                              hipStream_t stream)
{
  const float* x  = (const float*)d_in[0];
  const float* Wq = (const float*)d_in[1];
  const float* bq = (const float*)d_in[2];
  const float* Wk = (const float*)d_in[3];
  const float* bk = (const float*)d_in[4];
  const float* Wv = (const float*)d_in[5];
  const float* bv = (const float*)d_in[6];
  const float* Wo = (const float*)d_in[7];
  const float* bo = (const float*)d_in[8];
  const float* Wc = (const float*)d_in[9];
  const float* bc = (const float*)d_in[10];
  float* out = (float*)d_out;

  const size_t NE = (size_t)2048 * 1024;
  const size_t M1 = (size_t)1024 * 1024;
  float* Q   = (float*)d_ws;
  float* Kf  = Q + NE;
  float* Vf  = Kf + NE;
  float* Kc  = Vf + NE;
  float* Vc  = Kc + NE;
  float* at  = Vc + NE;
  double* kn = (double*)(at + NE);
  double* tail = kn + 32768;

  const size_t fixedB = 6 * NE * 4 + 32768 * 8;
  const size_t dotPairB = (size_t)Tn * Cn * 8;   // 8 MiB per (b,h) pair
  if (ws_size < fixedB) return;

  size_t rem = ws_size - fixedB;
  double* dotp; int G;
  if      (rem >= 32 * dotPairB) { G = 32; dotp = tail; }
  else if (rem >= 16 * dotPairB) { G = 16; dotp = tail; }
  else if (rem >=  8 * dotPairB) { G = 8;  dotp = tail; }
  else if (rem >=  4 * dotPairB) { G = 4;  dotp = tail; }
  else if (rem >=  2 * dotPairB) { G = 2;  dotp = tail; }
  else { G = 2; dotp = (double*)Kf; }  // Kf+Vf dead by then (16 MiB)

  dim3 blk(256, 1, 1);

  // Q + K projections merged (DUAL mode: z=0 -> Wq/bq/Q, z=1 -> Wk/bk/Kf)
  f64sel_k<float, true, 1, 2><<<dim3(16, 32, 2), blk, 0, stream>>>(
      x, Wq, Wk, bq, bk, Q, Kf, 1024, 1024, 1024, 1024, 0, 0, 0);
  // Value-path V projection (dbuf)
  mfma_gemm_k<true, 1><<<dim3(16, 32, 1), blk, 0, stream>>>(
      x, Wv, bv, Vf, 1024, 1024, 1024, 1024, 0, 0);

  // Compress: Kc (f64-MFMA dbuf), Vc (value MFMA dbuf), z = batch
  f64sel_k<float, false, 2, 0><<<dim3(16, 16, 2), blk, 0, stream>>>(
      Wc, Kf, nullptr, bc, nullptr, Kc, nullptr,
      1024, 1024, 1024, 1024, (long long)M1, (long long)M1, 0);
  mfma_gemm_k<false, 2><<<dim3(16, 16, 2), blk, 0, stream>>>(
      Wc, Vf, bc, Vc, 1024, 1024, 1024, 1024, (long long)M1, (long long)M1);

  kn_k2<<<dim3(128), blk, 0, stream>>>(Kc, kn);

  // Dot planes (f64-MFMA SIM dbuf) + fused topk/softmax/PV
  for (int gb = 0; gb < 32; gb += G) {
    f64sel_k<double, true, 0, 1><<<dim3(16, 16, G), blk, 0, stream>>>(
        Q, Kc, nullptr, nullptr, nullptr, dotp, nullptr,
        64, 1024, 1024, 1024, 0, 0, gb);
    topk_attn_k<<<dim3(256 * G), blk, 0, stream>>>(dotp, kn, Vc, at, gb);
  }

  // Output projection (dbuf)
  mfma_gemm_k<true, 1><<<dim3(16, 32, 1), blk, 0, stream>>>(
      at, Wo, bo, out, 1024, 1024, 1024, 1024, 0, 0);
}